// Round 19
// baseline (266.612 us; speedup 1.0000x reference)
//
#include <hip/hip_runtime.h>
#include <cstdint>
#include <cstddef>

#define B_  2
#define T_  2048
#define D_  1024
#define H_  16
#define HS_ 64
#define MTOT (B_*T_)   // 4096

typedef unsigned short u16;
typedef __attribute__((ext_vector_type(8))) __bf16 bf16x8;
typedef __attribute__((ext_vector_type(4))) float f32x4;

__device__ __forceinline__ u16 f2bf(float f) {
  unsigned int u = __builtin_bit_cast(unsigned int, f);
  u += 0x7fffu + ((u >> 16) & 1u);
  return (u16)(u >> 16);
}

__device__ __forceinline__ unsigned cvtpk(float lo, float hi) {
  unsigned r;
  asm("v_cvt_pk_bf16_f32 %0, %1, %2" : "=v"(r) : "v"(lo), "v"(hi));
  return r;
}

__device__ __forceinline__ void gload16(const u16* g, u16* l) {
  __builtin_amdgcn_global_load_lds((const __attribute__((address_space(1))) void*)g,
                                   (__attribute__((address_space(3))) void*)l, 16, 0, 0);
}

// ---------------- QKV weight transpose + fp32->bf16 (3 srcs, one dispatch) --
__global__ __launch_bounds__(256) void transpose_qkv(const float* __restrict__ wq,
                                                     const float* __restrict__ wk,
                                                     const float* __restrict__ wv,
                                                     u16* __restrict__ out) {
  __shared__ float tile[32][33];
  const int R = 1024, C = 64;
  int z = blockIdx.z, sel = z >> 4, zl = z & 15;
  const float* src = (sel == 0 ? wq : (sel == 1 ? wk : wv)) + (size_t)zl * R * C;
  u16* dst = out + (size_t)sel * 1024 * 1024 + (size_t)zl * R * C;
  int c0 = blockIdx.x * 32, r0 = blockIdx.y * 32;
  int tx = threadIdx.x & 31, ty = threadIdx.x >> 5;
#pragma unroll
  for (int k = 0; k < 4; ++k)
    tile[ty + k*8][tx] = src[(size_t)(r0 + ty + k*8) * C + c0 + tx];
  __syncthreads();
#pragma unroll
  for (int k = 0; k < 4; ++k)
    dst[(size_t)(c0 + ty + k*8) * R + r0 + tx] = f2bf(tile[tx][ty + k*8]);
}

// ---------------- Wp/W1/W2 transpose + fp32->bf16, one flat dispatch --------
__global__ __launch_bounds__(256) void transpose_rest(
    const float* __restrict__ Wp, const float* __restrict__ W1,
    const float* __restrict__ W2, u16* __restrict__ wp_t,
    u16* __restrict__ w1_t, u16* __restrict__ w2_t) {
  __shared__ float tile[32][33];
  int f = blockIdx.x;
  const float* src; u16* dst; int R, C, xx, yy;
  if (f < 1024)      { src = Wp; dst = wp_t; R = 1024; C = 1024; xx = f & 31;  yy = f >> 5; }
  else if (f < 5120) { int f2 = f - 1024; src = W1; dst = w1_t; R = 1024; C = 4096; xx = f2 & 127; yy = f2 >> 7; }
  else               { int f2 = f - 5120; src = W2; dst = w2_t; R = 4096; C = 1024; xx = f2 & 31;  yy = f2 >> 5; }
  int c0 = xx * 32, r0 = yy * 32;
  int tx = threadIdx.x & 31, ty = threadIdx.x >> 5;
#pragma unroll
  for (int k = 0; k < 4; ++k)
    tile[ty + k*8][tx] = src[(size_t)(r0 + ty + k*8) * C + c0 + tx];
  __syncthreads();
#pragma unroll
  for (int k = 0; k < 4; ++k)
    dst[(size_t)(c0 + ty + k*8) * R + r0 + tx] = f2bf(tile[tx][ty + k*8]);
}

// ---------------- layernorm ----------------
__global__ __launch_bounds__(256) void ln_kernel(const float* __restrict__ x,
                                                 const float* __restrict__ gg,
                                                 const float* __restrict__ be,
                                                 float* __restrict__ hf,
                                                 u16* __restrict__ hb) {
  int row = blockIdx.x;
  int t = threadIdx.x;
  const float* xr = x + (size_t)row * D_;
  float4 xv = *(const float4*)&xr[t * 4];
  float s  = xv.x + xv.y + xv.z + xv.w;
  float ss = xv.x*xv.x + xv.y*xv.y + xv.z*xv.z + xv.w*xv.w;
#pragma unroll
  for (int m = 1; m < 64; m <<= 1) { s += __shfl_xor(s, m); ss += __shfl_xor(ss, m); }
  __shared__ float red[8];
  int lane = t & 63, wv = t >> 6;
  if (lane == 0) { red[wv] = s; red[4 + wv] = ss; }
  __syncthreads();
  s  = red[0] + red[1] + red[2] + red[3];
  ss = red[4] + red[5] + red[6] + red[7];
  float mu  = s * (1.0f / D_);
  float var = ss * (1.0f / D_) - mu * mu;
  float rs  = rsqrtf(var + 1e-5f);
  float4 gv = *(const float4*)&gg[t * 4];
  float4 bv = *(const float4*)&be[t * 4];
  float4 hv;
  hv.x = (xv.x - mu) * rs * gv.x + bv.x;
  hv.y = (xv.y - mu) * rs * gv.y + bv.y;
  hv.z = (xv.z - mu) * rs * gv.z + bv.z;
  hv.w = (xv.w - mu) * rs * gv.w + bv.w;
  *(float4*)&hf[(size_t)row * D_ + t * 4] = hv;
  uint2 pk;
  pk.x = (unsigned)f2bf(hv.x) | ((unsigned)f2bf(hv.y) << 16);
  pk.y = (unsigned)f2bf(hv.z) | ((unsigned)f2bf(hv.w) << 16);
  *(uint2*)&hb[(size_t)row * D_ + t * 4] = pk;
}

// ---------------- 256x192 bf16 MFMA GEMM (2-phase, 8 waves) — QKV ----------
// Grid 16x16 = 256 blocks = exactly 1/CU. Per wave 128x48 (acc[8][3]).
// EPI 0: Q,K -> bf16 [B,T,D]; V -> [B,H,HS,T] packed uint2.
template<int EPI>
__global__ __launch_bounds__(512, 2) void gemm256(
    const u16* __restrict__ A, const u16* __restrict__ Bt,
    const float* __restrict__ bias0, const float* __restrict__ bias1,
    const float* __restrict__ bias2,
    u16* __restrict__ o0, u16* __restrict__ o1, u16* __restrict__ o2,
    int M, int N, int K) {
  __shared__ __align__(16) u16 As[2][256 * 64];
  __shared__ __align__(16) u16 Bs[2][192 * 64];
  const int tid = threadIdx.x;
  const int lane = tid & 63, w = tid >> 6;
  const int m0 = blockIdx.y * 256, n0 = blockIdx.x * 192;
  const int rA = lane & 15, g = lane >> 4;
  const int wm = (w >> 2) * 128, wn = (w & 3) * 48;
  const int sxa = rA & 7;

  f32x4 acc[8][3] = {};

  auto stage = [&](int t, int bufi) {
#pragma unroll
    for (int i = 0; i < 4; ++i) {              // A: 2048 chunks
      int c = i * 512 + tid;
      int row = c >> 3;
      int ss = (c & 7) ^ (row & 7);
      gload16(A + (size_t)(m0 + row) * K + t * 64 + ss * 8,
              &As[bufi][0] + (size_t)(i * 512 + w * 64) * 8);
    }
#pragma unroll
    for (int i = 0; i < 3; ++i) {              // B: 1536 chunks (192 rows)
      int c = i * 512 + tid;
      int row = c >> 3;
      int ss = (c & 7) ^ (row & 7);
      gload16(Bt + (size_t)(n0 + row) * K + t * 64 + ss * 8,
              &Bs[bufi][0] + (size_t)(i * 512 + w * 64) * 8);
    }
  };

  stage(0, 0);

  const int nk = K >> 6;
  for (int t = 0; t < nk; ++t) {
    __syncthreads();
    const int buf = t & 1;
    if (t + 1 < nk) stage(t + 1, buf ^ 1);

    bf16x8 bfr[3][2];
#pragma unroll
    for (int j = 0; j < 3; ++j) {
      int br = wn + j * 16 + rA;
#pragma unroll
      for (int kk = 0; kk < 2; ++kk)
        bfr[j][kk] = *(const bf16x8*)&Bs[buf][br * 64 + (((kk * 4 + g) ^ sxa) << 3)];
    }
#pragma unroll
    for (int i = 0; i < 8; ++i) {
      int ar = wm + i * 16 + rA;
      bf16x8 a0 = *(const bf16x8*)&As[buf][ar * 64 + ((g ^ sxa) << 3)];
      bf16x8 a1 = *(const bf16x8*)&As[buf][ar * 64 + (((4 + g) ^ sxa) << 3)];
#pragma unroll
      for (int j = 0; j < 3; ++j) {
        acc[i][j] = __builtin_amdgcn_mfma_f32_16x16x32_bf16(a0, bfr[j][0], acc[i][j], 0, 0, 0);
        acc[i][j] = __builtin_amdgcn_mfma_f32_16x16x32_bf16(a1, bfr[j][1], acc[i][j], 0, 0, 0);
      }
    }
  }

#pragma unroll
  for (int i = 0; i < 8; ++i) {
#pragma unroll
    for (int j = 0; j < 3; ++j) {
      int col = n0 + wn + j * 16 + rA;
      int sel = col >> 10, nn = col & 1023;
      int row0 = m0 + wm + i * 16 + g * 4;
      if (sel == 2) {
        // V: write transposed [B,H,HS,T]; 4 fragment rows = 4 consecutive t
        float bb = bias2[nn];
        int bb_ = row0 >> 11, t0 = row0 & 2047;
        uint2 pkv;
        pkv.x = cvtpk(acc[i][j][0] + bb, acc[i][j][1] + bb);
        pkv.y = cvtpk(acc[i][j][2] + bb, acc[i][j][3] + bb);
        *(uint2*)&o2[((size_t)(bb_ * 1024 + nn)) * 2048 + t0] = pkv;
      } else {
        const float* bp = sel == 0 ? bias0 : bias1;
        u16* op = sel == 0 ? o0 : o1;
#pragma unroll
        for (int r = 0; r < 4; ++r)
          op[(size_t)(row0 + r) * 1024 + nn] = f2bf(acc[i][j][r] + bp[nn]);
      }
    }
  }
}

// ---------------- 128xTN bf16 MFMA GEMM (3-buf, depth-2, counted vmcnt(4)) --
// T5: s_setprio around the MFMA cluster — with 2-4 independent blocks/CU at
// different pipeline phases, MFMA-entering waves preempt staging waves.
// EPI 1: tanh-GELU(v+bias) -> bf16 (FF1, TN=64, 4 blk/CU) ;
// EPI 2: +bias+res -> f32 (proj, TN=64) ; EPI 3: f32 split-K partial (FF2, TN=128).
template<int EPI, int TN>
__global__ __launch_bounds__(256) void gemm_bt(
    const u16* __restrict__ A, const u16* __restrict__ Bt,
    const float* __restrict__ bias0, const float* __restrict__ res,
    float* __restrict__ outf, float* __restrict__ p1, u16* __restrict__ ob,
    int M, int N, int K, int kLen) {
  constexpr int NJ = TN / 32;                 // B fragments per wave
  __shared__ __align__(16) u16 As[3][128 * 32];
  __shared__ __align__(16) u16 Bs[3][TN * 32];
  const int tid = threadIdx.x;
  const int lane = tid & 63, wv = tid >> 6;
  const int m0 = blockIdx.y * 128, n0 = blockIdx.x * TN;
  const int kOff = blockIdx.z * kLen;
  const int rA = lane & 15, g = lane >> 4;
  const int wm = (wv >> 1) * 64, wn = (wv & 1) * (TN / 2);
  const int sx = (rA >> 1) & 3;

  f32x4 acc[4][NJ] = {};

  auto stage = [&](int tt, int bufi) {
#pragma unroll
    for (int p = 0; p < 2; ++p) {
      int c = (p * 4 + wv) * 64 + lane;
      int row = c >> 2;
      int s = (c & 3) ^ ((row >> 1) & 3);
      gload16(A + (size_t)(m0 + row) * K + kOff + tt * 32 + s * 8,
              &As[bufi][0] + (size_t)(p * 4 + wv) * 512);
    }
#pragma unroll
    for (int p = 0; p < TN / 64; ++p) {
      int c = (p * 4 + wv) * 64 + lane;
      int row = c >> 2;
      int s = (c & 3) ^ ((row >> 1) & 3);
      gload16(Bt + (size_t)(n0 + row) * K + kOff + tt * 32 + s * 8,
              &Bs[bufi][0] + (size_t)(p * 4 + wv) * 512);
    }
  };

  const int nk = kLen >> 5;
  stage(0, 0);
  stage(1, 1);

  int cur = 0, nxt = 2;
  for (int t = 0; t < nk; ++t) {
    if (t + 1 < nk) asm volatile("s_waitcnt vmcnt(4)" ::: "memory");
    else            asm volatile("s_waitcnt vmcnt(0)" ::: "memory");
    __builtin_amdgcn_s_barrier();
    __builtin_amdgcn_sched_barrier(0);
    if (t + 2 < nk) stage(t + 2, nxt);

    bf16x8 a[4], b[NJ];
#pragma unroll
    for (int i = 0; i < 4; ++i)
      a[i] = *(const bf16x8*)&As[cur][(wm + i * 16 + rA) * 32 + ((g ^ sx) << 3)];
#pragma unroll
    for (int j = 0; j < NJ; ++j)
      b[j] = *(const bf16x8*)&Bs[cur][(wn + j * 16 + rA) * 32 + ((g ^ sx) << 3)];
    __builtin_amdgcn_s_setprio(1);
#pragma unroll
    for (int i = 0; i < 4; ++i)
#pragma unroll
      for (int j = 0; j < NJ; ++j)
        acc[i][j] = __builtin_amdgcn_mfma_f32_16x16x32_bf16(a[i], b[j], acc[i][j], 0, 0, 0);
    __builtin_amdgcn_s_setprio(0);

    cur = (cur == 2) ? 0 : cur + 1;
    nxt = (nxt == 2) ? 0 : nxt + 1;
  }

#pragma unroll
  for (int i = 0; i < 4; ++i) {
#pragma unroll
    for (int j = 0; j < NJ; ++j) {
#pragma unroll
      for (int r = 0; r < 4; ++r) {
        int row = m0 + wm + i * 16 + g * 4 + r;
        int col = n0 + wn + j * 16 + rA;
        float v = acc[i][j][r];
        if constexpr (EPI == 1) {
          v += bias0[col];
          float z = 0.7978845608f * (v + 0.044715f * v * v * v);
          z = fminf(z, 18.0f);
          float e = __builtin_amdgcn_exp2f(z * 2.8853900817779268f);
          v = v * e / (e + 1.0f);
          ob[(size_t)row * N + col] = f2bf(v);
        } else if constexpr (EPI == 2) {
          v += bias0[col] + res[(size_t)row * N + col];
          outf[(size_t)row * N + col] = v;
        } else {
          float* dst = blockIdx.z ? p1 : outf;
          dst[(size_t)row * N + col] = v;
        }
      }
    }
  }
}

// out = p0 + p1 + bias[col] + res  (FF2 split-K reduce, N=1024)
__global__ __launch_bounds__(256) void reduce_ff2(const float* __restrict__ p0,
                                                  const float* __restrict__ p1,
                                                  const float* __restrict__ bias,
                                                  const float* __restrict__ res,
                                                  float* __restrict__ out) {
  int i = (blockIdx.x * 256 + threadIdx.x) * 4;
  float4 a = *(const float4*)&p0[i];
  float4 b = *(const float4*)&p1[i];
  float4 r = *(const float4*)&res[i];
  float4 bb = *(const float4*)&bias[i & 1023];
  float4 o;
  o.x = a.x + b.x + r.x + bb.x;
  o.y = a.y + b.y + r.y + bb.y;
  o.z = a.z + b.z + r.z + bb.z;
  o.w = a.w + b.w + r.w + bb.w;
  *(float4*)&out[i] = o;
}

// ---------------- flash attention (QBLK=128, 8 waves, swapped QK^T) --------
__global__ __launch_bounds__(512) void attn_kernel(const u16* __restrict__ qg,
                                                   const u16* __restrict__ kg,
                                                   const u16* __restrict__ vtg,
                                                   u16* __restrict__ og) {
  const int wg = blockIdx.x;
  const int qt = wg & 15;            // 16 q-tiles of 128 rows
  const int h  = (wg >> 4) & 15;
  const int b  = wg >> 8;
  const int tid = threadIdx.x, lane = tid & 63, wv = tid >> 6;
  const int q0 = qt * 128 + wv * 16;
  const int rA = lane & 15, g = lane >> 4;
  const int rx = rA & 7;

  __shared__ __align__(16) u16 Ks[2][64 * 64];   // [key][dim]
  __shared__ __align__(16) u16 Vs[2][64 * 64];   // [hs][key]
  __shared__ __align__(16) u16 Ps[8][16 * 64];   // per-wave P^T

  const size_t qoff = ((size_t)b * T_ + q0 + rA) * D_ + h * HS_ + g * 8;
  const bf16x8 aq0 = *(const bf16x8*)&qg[qoff];
  const bf16x8 aq1 = *(const bf16x8*)&qg[qoff + 32];

  const u16* kbase = kg + (size_t)b * T_ * D_ + h * HS_;
  const u16* vbase = vtg + ((size_t)b * H_ + h) * HS_ * T_;

  const float cfold = 0.18033688011112042f;  // HS^-0.5 * log2(e)
  float mrun = -1e30f;
  f32x4 oacc[4] = {};
  f32x4 lacc = {};
  bf16x8 ones;
#pragma unroll
  for (int e = 0; e < 8; ++e) ones[e] = (__bf16)1.0f;

  auto stage = [&](int t, int buf) {
    int row = tid >> 3, s = tid & 7;
    int ss = s ^ (row & 7);
    gload16(kbase + ((size_t)t * 64 + row) * D_ + ss * 8,
            &Ks[buf][0] + (size_t)(wv * 64) * 8);
    gload16(vbase + (size_t)row * T_ + t * 64 + ss * 8,
            &Vs[buf][0] + (size_t)(wv * 64) * 8);
  };

  stage(0, 0);

  const int NT = T_ / 64;
  for (int t = 0; t < NT; ++t) {
    __syncthreads();
    const int buf = t & 1;
    if (t + 1 < NT) stage(t + 1, buf ^ 1);

    const u16* kb = &Ks[buf][0];
    f32x4 sc[4];
    __builtin_amdgcn_s_setprio(1);
#pragma unroll
    for (int st = 0; st < 4; ++st) {
      bf16x8 k0 = *(const bf16x8*)&kb[(st * 16 + rA) * 64 + ((g ^ rx) << 3)];
      bf16x8 k1 = *(const bf16x8*)&kb[(st * 16 + rA) * 64 + (((4 + g) ^ rx) << 3)];
      f32x4 z = {};
      z = __builtin_amdgcn_mfma_f32_16x16x32_bf16(k0, aq0, z, 0, 0, 0);
      z = __builtin_amdgcn_mfma_f32_16x16x32_bf16(k1, aq1, z, 0, 0, 0);
      sc[st] = z;
    }
    __builtin_amdgcn_s_setprio(0);

    float a0 = fmaxf(fmaxf(sc[0][0], sc[0][1]), fmaxf(sc[0][2], sc[0][3]));
    float a1 = fmaxf(fmaxf(sc[1][0], sc[1][1]), fmaxf(sc[1][2], sc[1][3]));
    float a2 = fmaxf(fmaxf(sc[2][0], sc[2][1]), fmaxf(sc[2][2], sc[2][3]));
    float a3 = fmaxf(fmaxf(sc[3][0], sc[3][1]), fmaxf(sc[3][2], sc[3][3]));
    float mx = fmaxf(fmaxf(a0, a1), fmaxf(a2, a3));
    mx = fmaxf(mx, __shfl_xor(mx, 16));
    mx = fmaxf(mx, __shfl_xor(mx, 32));
    float tm = mx * cfold;

    if (__any(tm > mrun + 8.0f)) {           // defer-max (T13)
      float mnew = fmaxf(mrun, tm);
      float sca = __builtin_amdgcn_exp2f(mrun - mnew);
      mrun = mnew;
      lacc *= sca;
#pragma unroll
      for (int f = 0; f < 4; ++f) oacc[f] *= sca;
    }

    float p[16];
#pragma unroll
    for (int st = 0; st < 4; ++st)
#pragma unroll
      for (int r = 0; r < 4; ++r)
        p[st * 4 + r] = __builtin_amdgcn_exp2f(__builtin_fmaf(sc[st][r], cfold, -mrun));

    char* psb = (char*)&Ps[wv][0];
#pragma unroll
    for (int st = 0; st < 4; ++st) {
      uint2 w;
      w.x = cvtpk(p[st * 4 + 0], p[st * 4 + 1]);
      w.y = cvtpk(p[st * 4 + 2], p[st * 4 + 3]);
      int slot = st * 2 + (g >> 1);
      *(uint2*)&psb[rA * 128 + (((slot ^ rx)) << 4) + ((g & 1) << 3)] = w;
    }
    bf16x8 pf0 = *(const bf16x8*)&psb[rA * 128 + ((g ^ rx) << 4)];
    bf16x8 pf1 = *(const bf16x8*)&psb[rA * 128 + (((4 + g) ^ rx) << 4)];

    const u16* vbl = &Vs[buf][0];
    __builtin_amdgcn_s_setprio(1);
#pragma unroll
    for (int f = 0; f < 4; ++f) {
      bf16x8 v0 = *(const bf16x8*)&vbl[(f * 16 + rA) * 64 + ((g ^ rx) << 3)];
      bf16x8 v1 = *(const bf16x8*)&vbl[(f * 16 + rA) * 64 + (((4 + g) ^ rx) << 3)];
      oacc[f] = __builtin_amdgcn_mfma_f32_16x16x32_bf16(v0, pf0, oacc[f], 0, 0, 0);
      oacc[f] = __builtin_amdgcn_mfma_f32_16x16x32_bf16(v1, pf1, oacc[f], 0, 0, 0);
    }
    lacc = __builtin_amdgcn_mfma_f32_16x16x32_bf16(ones, pf0, lacc, 0, 0, 0);
    lacc = __builtin_amdgcn_mfma_f32_16x16x32_bf16(ones, pf1, lacc, 0, 0, 0);
    __builtin_amdgcn_s_setprio(0);
  }

  float linv = 1.0f / lacc[0];
#pragma unroll
  for (int f = 0; f < 4; ++f) {
    uint2 w;
    w.x = cvtpk(oacc[f][0] * linv, oacc[f][1] * linv);
    w.y = cvtpk(oacc[f][2] * linv, oacc[f][3] * linv);
    *(uint2*)&og[((size_t)b * T_ + q0 + rA) * D_ + h * HS_ + f * 16 + g * 4] = w;
  }
}

// ---------------- host launch ----------------
extern "C" void kernel_launch(void* const* d_in, const int* in_sizes, int n_in,
                              void* d_out, int out_size, void* d_ws, size_t ws_size,
                              hipStream_t stream) {
  const float* x   = (const float*)d_in[0];
  const float* Wq  = (const float*)d_in[1];
  const float* bq  = (const float*)d_in[2];
  const float* Wk  = (const float*)d_in[3];
  const float* bk  = (const float*)d_in[4];
  const float* Wv  = (const float*)d_in[5];
  const float* bv  = (const float*)d_in[6];
  const float* Wp  = (const float*)d_in[7];
  const float* bp  = (const float*)d_in[8];
  const float* W1  = (const float*)d_in[9];
  const float* b1  = (const float*)d_in[10];
  const float* W2  = (const float*)d_in[11];
  const float* b2  = (const float*)d_in[12];
  const float* g1  = (const float*)d_in[13];
  const float* be1 = (const float*)d_in[14];
  const float* g2  = (const float*)d_in[15];
  const float* be2 = (const float*)d_in[16];
  float* out = (float*)d_out;

  char* w = (char*)d_ws;
  auto alloc = [&](size_t bytes) { char* p = w; w += (bytes + 255) & ~(size_t)255; return p; };
  const size_t MD = (size_t)MTOT * D_;

  float* h_f    = (float*)alloc(MD * 4);
  u16*   h_b    = (u16*)  alloc(MD * 2);
  u16*   wqkv_t = (u16*)  alloc(3 * (size_t)D_ * D_ * 2);
  u16*   wp_t   = (u16*)  alloc((size_t)D_ * D_ * 2);
  u16*   w1_t   = (u16*)  alloc((size_t)D_ * 4 * D_ * 2);
  u16*   w2_t   = (u16*)  alloc((size_t)D_ * 4 * D_ * 2);
  u16*   q_b    = (u16*)  alloc(MD * 2);
  u16*   k_b    = (u16*)  alloc(MD * 2);
  u16*   v_b    = (u16*)  alloc(MD * 2);   // unused as V now, kept: part of ff1_b span
  u16*   vt_b   = (u16*)  alloc(MD * 2);
  u16*   o_b    = (u16*)  alloc(MD * 2);
  float* hat_f  = (float*)alloc(MD * 4);
  u16*   ff1_b  = q_b;            // [4096,4096] bf16 spans q_b..vt_b
  float* h2_f   = h_f;
  u16*   h2_b   = h_b;
  float* pf0    = hat_f;          // FF2 split-K partial z=0 (hat_f dead after ln2)
  float* pf1    = (float*)h_b;    // partial z=1: h_b+wqkv_t+wp_t = 16MB, all dead
  (void)v_b;

  dim3 blk(256);

  transpose_qkv<<<dim3(2, 32, 48), blk, 0, stream>>>(Wq, Wk, Wv, wqkv_t);
  transpose_rest<<<dim3(9216), blk, 0, stream>>>(Wp, W1, W2, wp_t, w1_t, w2_t);

  ln_kernel<<<dim3(MTOT), blk, 0, stream>>>(x, g1, be1, h_f, h_b);

  // QKV: 256x192 tiles -> grid 16x16 = 256 blocks = 1/CU exactly
  gemm256<0><<<dim3(16, 16), dim3(512), 0, stream>>>(h_b, wqkv_t, bq, bk, bv,
      q_b, k_b, vt_b, MTOT, 3072, 1024);

  // attn: QBLK=128, 8 waves, grid 512
  attn_kernel<<<dim3(B_ * H_ * (T_ / 128)), dim3(512), 0, stream>>>(q_b, k_b, vt_b, o_b);

  // proj: TN=64 -> 512 blocks = 2 blocks/CU
  gemm_bt<2, 64><<<dim3(16, 32, 1), blk, 0, stream>>>(o_b, wp_t, bp, h_f, hat_f,
      nullptr, nullptr, MTOT, 1024, 1024, 1024);

  ln_kernel<<<dim3(MTOT), blk, 0, stream>>>(hat_f, g2, be2, h2_f, h2_b);

  // FF1: TN=64 -> 2048 blocks, 36KB LDS -> 4 blocks/CU
  gemm_bt<1, 64><<<dim3(64, 32, 1), blk, 0, stream>>>(h2_b, w1_t, b1, nullptr,
      nullptr, nullptr, ff1_b, MTOT, 4096, 1024, 1024);

  // FF2: TN=128 split-K x2 (measured-best): z=0 -> pf0, z=1 -> pf1
  gemm_bt<3, 128><<<dim3(8, 32, 2), blk, 0, stream>>>(ff1_b, w2_t, nullptr, nullptr,
      pf0, pf1, nullptr, MTOT, 1024, 4096, 2048);

  reduce_ff2<<<dim3(MTOT), blk, 0, stream>>>(pf0, pf1, b2, h2_f, out);
}

// Round 20
// 261.673 us; speedup vs baseline: 1.0189x; 1.0189x over previous
//
#include <hip/hip_runtime.h>
#include <cstdint>
#include <cstddef>

#define B_  2
#define T_  2048
#define D_  1024
#define H_  16
#define HS_ 64
#define MTOT (B_*T_)   // 4096

typedef unsigned short u16;
typedef __attribute__((ext_vector_type(8))) __bf16 bf16x8;
typedef __attribute__((ext_vector_type(4))) float f32x4;

__device__ __forceinline__ u16 f2bf(float f) {
  unsigned int u = __builtin_bit_cast(unsigned int, f);
  u += 0x7fffu + ((u >> 16) & 1u);
  return (u16)(u >> 16);
}

__device__ __forceinline__ float bf2f(u16 h) {
  return __builtin_bit_cast(float, (unsigned)h << 16);
}

__device__ __forceinline__ unsigned cvtpk(float lo, float hi) {
  unsigned r;
  asm("v_cvt_pk_bf16_f32 %0, %1, %2" : "=v"(r) : "v"(lo), "v"(hi));
  return r;
}

__device__ __forceinline__ void gload16(const u16* g, u16* l) {
  __builtin_amdgcn_global_load_lds((const __attribute__((address_space(1))) void*)g,
                                   (__attribute__((address_space(3))) void*)l, 16, 0, 0);
}

// ---------------- QKV weight transpose + fp32->bf16 (3 srcs, one dispatch) --
__global__ __launch_bounds__(256) void transpose_qkv(const float* __restrict__ wq,
                                                     const float* __restrict__ wk,
                                                     const float* __restrict__ wv,
                                                     u16* __restrict__ out) {
  __shared__ float tile[32][33];
  const int R = 1024, C = 64;
  int z = blockIdx.z, sel = z >> 4, zl = z & 15;
  const float* src = (sel == 0 ? wq : (sel == 1 ? wk : wv)) + (size_t)zl * R * C;
  u16* dst = out + (size_t)sel * 1024 * 1024 + (size_t)zl * R * C;
  int c0 = blockIdx.x * 32, r0 = blockIdx.y * 32;
  int tx = threadIdx.x & 31, ty = threadIdx.x >> 5;
#pragma unroll
  for (int k = 0; k < 4; ++k)
    tile[ty + k*8][tx] = src[(size_t)(r0 + ty + k*8) * C + c0 + tx];
  __syncthreads();
#pragma unroll
  for (int k = 0; k < 4; ++k)
    dst[(size_t)(c0 + ty + k*8) * R + r0 + tx] = f2bf(tile[tx][ty + k*8]);
}

// ---------------- Wp/W1/W2 transpose + fp32->bf16, one flat dispatch --------
__global__ __launch_bounds__(256) void transpose_rest(
    const float* __restrict__ Wp, const float* __restrict__ W1,
    const float* __restrict__ W2, u16* __restrict__ wp_t,
    u16* __restrict__ w1_t, u16* __restrict__ w2_t) {
  __shared__ float tile[32][33];
  int f = blockIdx.x;
  const float* src; u16* dst; int R, C, xx, yy;
  if (f < 1024)      { src = Wp; dst = wp_t; R = 1024; C = 1024; xx = f & 31;  yy = f >> 5; }
  else if (f < 5120) { int f2 = f - 1024; src = W1; dst = w1_t; R = 1024; C = 4096; xx = f2 & 127; yy = f2 >> 7; }
  else               { int f2 = f - 5120; src = W2; dst = w2_t; R = 4096; C = 1024; xx = f2 & 31;  yy = f2 >> 5; }
  int c0 = xx * 32, r0 = yy * 32;
  int tx = threadIdx.x & 31, ty = threadIdx.x >> 5;
#pragma unroll
  for (int k = 0; k < 4; ++k)
    tile[ty + k*8][tx] = src[(size_t)(r0 + ty + k*8) * C + c0 + tx];
  __syncthreads();
#pragma unroll
  for (int k = 0; k < 4; ++k)
    dst[(size_t)(c0 + ty + k*8) * R + r0 + tx] = f2bf(tile[tx][ty + k*8]);
}

// ---------------- layernorm: fp32 in -> bf16 out only (residual also bf16) --
__global__ __launch_bounds__(256) void ln_kernel(const float* __restrict__ x,
                                                 const float* __restrict__ gg,
                                                 const float* __restrict__ be,
                                                 u16* __restrict__ hb) {
  int row = blockIdx.x;
  int t = threadIdx.x;
  const float* xr = x + (size_t)row * D_;
  float4 xv = *(const float4*)&xr[t * 4];
  float s  = xv.x + xv.y + xv.z + xv.w;
  float ss = xv.x*xv.x + xv.y*xv.y + xv.z*xv.z + xv.w*xv.w;
#pragma unroll
  for (int m = 1; m < 64; m <<= 1) { s += __shfl_xor(s, m); ss += __shfl_xor(ss, m); }
  __shared__ float red[8];
  int lane = t & 63, wv = t >> 6;
  if (lane == 0) { red[wv] = s; red[4 + wv] = ss; }
  __syncthreads();
  s  = red[0] + red[1] + red[2] + red[3];
  ss = red[4] + red[5] + red[6] + red[7];
  float mu  = s * (1.0f / D_);
  float var = ss * (1.0f / D_) - mu * mu;
  float rs  = rsqrtf(var + 1e-5f);
  float4 gv = *(const float4*)&gg[t * 4];
  float4 bv = *(const float4*)&be[t * 4];
  float4 hv;
  hv.x = (xv.x - mu) * rs * gv.x + bv.x;
  hv.y = (xv.y - mu) * rs * gv.y + bv.y;
  hv.z = (xv.z - mu) * rs * gv.z + bv.z;
  hv.w = (xv.w - mu) * rs * gv.w + bv.w;
  uint2 pk;
  pk.x = cvtpk(hv.x, hv.y);
  pk.y = cvtpk(hv.z, hv.w);
  *(uint2*)&hb[(size_t)row * D_ + t * 4] = pk;
}

// ---------------- 256x192 bf16 MFMA GEMM (2-phase, 8 waves) — QKV ----------
// Grid 16x16 = 256 blocks = exactly 1/CU. Per wave 128x48 (acc[8][3]).
// EPI 0: Q,K -> bf16 [B,T,D]; V -> [B,H,HS,T] packed uint2.
template<int EPI>
__global__ __launch_bounds__(512, 2) void gemm256(
    const u16* __restrict__ A, const u16* __restrict__ Bt,
    const float* __restrict__ bias0, const float* __restrict__ bias1,
    const float* __restrict__ bias2,
    u16* __restrict__ o0, u16* __restrict__ o1, u16* __restrict__ o2,
    int M, int N, int K) {
  __shared__ __align__(16) u16 As[2][256 * 64];
  __shared__ __align__(16) u16 Bs[2][192 * 64];
  const int tid = threadIdx.x;
  const int lane = tid & 63, w = tid >> 6;
  const int m0 = blockIdx.y * 256, n0 = blockIdx.x * 192;
  const int rA = lane & 15, g = lane >> 4;
  const int wm = (w >> 2) * 128, wn = (w & 3) * 48;
  const int sxa = rA & 7;

  f32x4 acc[8][3] = {};

  auto stage = [&](int t, int bufi) {
#pragma unroll
    for (int i = 0; i < 4; ++i) {              // A: 2048 chunks
      int c = i * 512 + tid;
      int row = c >> 3;
      int ss = (c & 7) ^ (row & 7);
      gload16(A + (size_t)(m0 + row) * K + t * 64 + ss * 8,
              &As[bufi][0] + (size_t)(i * 512 + w * 64) * 8);
    }
#pragma unroll
    for (int i = 0; i < 3; ++i) {              // B: 1536 chunks (192 rows)
      int c = i * 512 + tid;
      int row = c >> 3;
      int ss = (c & 7) ^ (row & 7);
      gload16(Bt + (size_t)(n0 + row) * K + t * 64 + ss * 8,
              &Bs[bufi][0] + (size_t)(i * 512 + w * 64) * 8);
    }
  };

  stage(0, 0);

  const int nk = K >> 6;
  for (int t = 0; t < nk; ++t) {
    __syncthreads();
    const int buf = t & 1;
    if (t + 1 < nk) stage(t + 1, buf ^ 1);

    bf16x8 bfr[3][2];
#pragma unroll
    for (int j = 0; j < 3; ++j) {
      int br = wn + j * 16 + rA;
#pragma unroll
      for (int kk = 0; kk < 2; ++kk)
        bfr[j][kk] = *(const bf16x8*)&Bs[buf][br * 64 + (((kk * 4 + g) ^ sxa) << 3)];
    }
#pragma unroll
    for (int i = 0; i < 8; ++i) {
      int ar = wm + i * 16 + rA;
      bf16x8 a0 = *(const bf16x8*)&As[buf][ar * 64 + ((g ^ sxa) << 3)];
      bf16x8 a1 = *(const bf16x8*)&As[buf][ar * 64 + (((4 + g) ^ sxa) << 3)];
#pragma unroll
      for (int j = 0; j < 3; ++j) {
        acc[i][j] = __builtin_amdgcn_mfma_f32_16x16x32_bf16(a0, bfr[j][0], acc[i][j], 0, 0, 0);
        acc[i][j] = __builtin_amdgcn_mfma_f32_16x16x32_bf16(a1, bfr[j][1], acc[i][j], 0, 0, 0);
      }
    }
  }

#pragma unroll
  for (int i = 0; i < 8; ++i) {
#pragma unroll
    for (int j = 0; j < 3; ++j) {
      int col = n0 + wn + j * 16 + rA;
      int sel = col >> 10, nn = col & 1023;
      int row0 = m0 + wm + i * 16 + g * 4;
      if (sel == 2) {
        // V: write transposed [B,H,HS,T]; 4 fragment rows = 4 consecutive t
        float bb = bias2[nn];
        int bb_ = row0 >> 11, t0 = row0 & 2047;
        uint2 pkv;
        pkv.x = cvtpk(acc[i][j][0] + bb, acc[i][j][1] + bb);
        pkv.y = cvtpk(acc[i][j][2] + bb, acc[i][j][3] + bb);
        *(uint2*)&o2[((size_t)(bb_ * 1024 + nn)) * 2048 + t0] = pkv;
      } else {
        const float* bp = sel == 0 ? bias0 : bias1;
        u16* op = sel == 0 ? o0 : o1;
#pragma unroll
        for (int r = 0; r < 4; ++r)
          op[(size_t)(row0 + r) * 1024 + nn] = f2bf(acc[i][j][r] + bp[nn]);
      }
    }
  }
}

// ---------------- 128xTN bf16 MFMA GEMM (3-buf, depth-2, counted vmcnt(4)) --
// EPI 1: tanh-GELU(v+bias) -> bf16 (FF1, TN=64, 4 blk/CU) ;
// EPI 2: +bias+res(bf16) -> f32 (proj, TN=64) ;
// EPI 3: f32 split-K partial (FF2, TN=128).
template<int EPI, int TN>
__global__ __launch_bounds__(256) void gemm_bt(
    const u16* __restrict__ A, const u16* __restrict__ Bt,
    const float* __restrict__ bias0, const u16* __restrict__ resb,
    float* __restrict__ outf, float* __restrict__ p1, u16* __restrict__ ob,
    int M, int N, int K, int kLen) {
  constexpr int NJ = TN / 32;                 // B fragments per wave
  __shared__ __align__(16) u16 As[3][128 * 32];
  __shared__ __align__(16) u16 Bs[3][TN * 32];
  const int tid = threadIdx.x;
  const int lane = tid & 63, wv = tid >> 6;
  const int m0 = blockIdx.y * 128, n0 = blockIdx.x * TN;
  const int kOff = blockIdx.z * kLen;
  const int rA = lane & 15, g = lane >> 4;
  const int wm = (wv >> 1) * 64, wn = (wv & 1) * (TN / 2);
  const int sx = (rA >> 1) & 3;

  f32x4 acc[4][NJ] = {};

  auto stage = [&](int tt, int bufi) {
#pragma unroll
    for (int p = 0; p < 2; ++p) {
      int c = (p * 4 + wv) * 64 + lane;
      int row = c >> 2;
      int s = (c & 3) ^ ((row >> 1) & 3);
      gload16(A + (size_t)(m0 + row) * K + kOff + tt * 32 + s * 8,
              &As[bufi][0] + (size_t)(p * 4 + wv) * 512);
    }
#pragma unroll
    for (int p = 0; p < TN / 64; ++p) {
      int c = (p * 4 + wv) * 64 + lane;
      int row = c >> 2;
      int s = (c & 3) ^ ((row >> 1) & 3);
      gload16(Bt + (size_t)(n0 + row) * K + kOff + tt * 32 + s * 8,
              &Bs[bufi][0] + (size_t)(p * 4 + wv) * 512);
    }
  };

  const int nk = kLen >> 5;
  stage(0, 0);
  stage(1, 1);

  int cur = 0, nxt = 2;
  for (int t = 0; t < nk; ++t) {
    if (t + 1 < nk) asm volatile("s_waitcnt vmcnt(4)" ::: "memory");
    else            asm volatile("s_waitcnt vmcnt(0)" ::: "memory");
    __builtin_amdgcn_s_barrier();
    __builtin_amdgcn_sched_barrier(0);
    if (t + 2 < nk) stage(t + 2, nxt);

    bf16x8 a[4], b[NJ];
#pragma unroll
    for (int i = 0; i < 4; ++i)
      a[i] = *(const bf16x8*)&As[cur][(wm + i * 16 + rA) * 32 + ((g ^ sx) << 3)];
#pragma unroll
    for (int j = 0; j < NJ; ++j)
      b[j] = *(const bf16x8*)&Bs[cur][(wn + j * 16 + rA) * 32 + ((g ^ sx) << 3)];
#pragma unroll
    for (int i = 0; i < 4; ++i)
#pragma unroll
      for (int j = 0; j < NJ; ++j)
        acc[i][j] = __builtin_amdgcn_mfma_f32_16x16x32_bf16(a[i], b[j], acc[i][j], 0, 0, 0);

    cur = (cur == 2) ? 0 : cur + 1;
    nxt = (nxt == 2) ? 0 : nxt + 1;
  }

#pragma unroll
  for (int i = 0; i < 4; ++i) {
#pragma unroll
    for (int j = 0; j < NJ; ++j) {
#pragma unroll
      for (int r = 0; r < 4; ++r) {
        int row = m0 + wm + i * 16 + g * 4 + r;
        int col = n0 + wn + j * 16 + rA;
        float v = acc[i][j][r];
        if constexpr (EPI == 1) {
          v += bias0[col];
          float z = 0.7978845608f * (v + 0.044715f * v * v * v);
          z = fminf(z, 18.0f);
          float e = __builtin_amdgcn_exp2f(z * 2.8853900817779268f);
          v = v * e / (e + 1.0f);
          ob[(size_t)row * N + col] = f2bf(v);
        } else if constexpr (EPI == 2) {
          v += bias0[col] + bf2f(resb[(size_t)row * N + col]);
          outf[(size_t)row * N + col] = v;
        } else {
          float* dst = blockIdx.z ? p1 : outf;
          dst[(size_t)row * N + col] = v;
        }
      }
    }
  }
}

// out = p0 + p1 + bias[col] + res(bf16)  (FF2 split-K reduce, N=1024)
__global__ __launch_bounds__(256) void reduce_ff2(const float* __restrict__ p0,
                                                  const float* __restrict__ p1,
                                                  const float* __restrict__ bias,
                                                  const u16* __restrict__ resb,
                                                  float* __restrict__ out) {
  int i = (blockIdx.x * 256 + threadIdx.x) * 4;
  float4 a = *(const float4*)&p0[i];
  float4 b = *(const float4*)&p1[i];
  ushort4 hv = *(const ushort4*)&resb[i];
  float4 bb = *(const float4*)&bias[i & 1023];
  float4 o;
  o.x = a.x + b.x + bf2f(hv.x) + bb.x;
  o.y = a.y + b.y + bf2f(hv.y) + bb.y;
  o.z = a.z + b.z + bf2f(hv.z) + bb.z;
  o.w = a.w + b.w + bf2f(hv.w) + bb.w;
  *(float4*)&out[i] = o;
}

// ---------------- flash attention (QBLK=128, 8 waves, swapped QK^T) --------
__global__ __launch_bounds__(512) void attn_kernel(const u16* __restrict__ qg,
                                                   const u16* __restrict__ kg,
                                                   const u16* __restrict__ vtg,
                                                   u16* __restrict__ og) {
  const int wg = blockIdx.x;
  const int qt = wg & 15;            // 16 q-tiles of 128 rows
  const int h  = (wg >> 4) & 15;
  const int b  = wg >> 8;
  const int tid = threadIdx.x, lane = tid & 63, wv = tid >> 6;
  const int q0 = qt * 128 + wv * 16;
  const int rA = lane & 15, g = lane >> 4;
  const int rx = rA & 7;

  __shared__ __align__(16) u16 Ks[2][64 * 64];   // [key][dim]
  __shared__ __align__(16) u16 Vs[2][64 * 64];   // [hs][key]
  __shared__ __align__(16) u16 Ps[8][16 * 64];   // per-wave P^T

  const size_t qoff = ((size_t)b * T_ + q0 + rA) * D_ + h * HS_ + g * 8;
  const bf16x8 aq0 = *(const bf16x8*)&qg[qoff];
  const bf16x8 aq1 = *(const bf16x8*)&qg[qoff + 32];

  const u16* kbase = kg + (size_t)b * T_ * D_ + h * HS_;
  const u16* vbase = vtg + ((size_t)b * H_ + h) * HS_ * T_;

  const float cfold = 0.18033688011112042f;  // HS^-0.5 * log2(e)
  float mrun = -1e30f;
  f32x4 oacc[4] = {};
  f32x4 lacc = {};
  bf16x8 ones;
#pragma unroll
  for (int e = 0; e < 8; ++e) ones[e] = (__bf16)1.0f;

  auto stage = [&](int t, int buf) {
    int row = tid >> 3, s = tid & 7;
    int ss = s ^ (row & 7);
    gload16(kbase + ((size_t)t * 64 + row) * D_ + ss * 8,
            &Ks[buf][0] + (size_t)(wv * 64) * 8);
    gload16(vbase + (size_t)row * T_ + t * 64 + ss * 8,
            &Vs[buf][0] + (size_t)(wv * 64) * 8);
  };

  stage(0, 0);

  const int NT = T_ / 64;
  for (int t = 0; t < NT; ++t) {
    __syncthreads();
    const int buf = t & 1;
    if (t + 1 < NT) stage(t + 1, buf ^ 1);

    const u16* kb = &Ks[buf][0];
    f32x4 sc[4];
    __builtin_amdgcn_s_setprio(1);
#pragma unroll
    for (int st = 0; st < 4; ++st) {
      bf16x8 k0 = *(const bf16x8*)&kb[(st * 16 + rA) * 64 + ((g ^ rx) << 3)];
      bf16x8 k1 = *(const bf16x8*)&kb[(st * 16 + rA) * 64 + (((4 + g) ^ rx) << 3)];
      f32x4 z = {};
      z = __builtin_amdgcn_mfma_f32_16x16x32_bf16(k0, aq0, z, 0, 0, 0);
      z = __builtin_amdgcn_mfma_f32_16x16x32_bf16(k1, aq1, z, 0, 0, 0);
      sc[st] = z;
    }
    __builtin_amdgcn_s_setprio(0);

    float a0 = fmaxf(fmaxf(sc[0][0], sc[0][1]), fmaxf(sc[0][2], sc[0][3]));
    float a1 = fmaxf(fmaxf(sc[1][0], sc[1][1]), fmaxf(sc[1][2], sc[1][3]));
    float a2 = fmaxf(fmaxf(sc[2][0], sc[2][1]), fmaxf(sc[2][2], sc[2][3]));
    float a3 = fmaxf(fmaxf(sc[3][0], sc[3][1]), fmaxf(sc[3][2], sc[3][3]));
    float mx = fmaxf(fmaxf(a0, a1), fmaxf(a2, a3));
    mx = fmaxf(mx, __shfl_xor(mx, 16));
    mx = fmaxf(mx, __shfl_xor(mx, 32));
    float tm = mx * cfold;

    if (__any(tm > mrun + 8.0f)) {           // defer-max (T13)
      float mnew = fmaxf(mrun, tm);
      float sca = __builtin_amdgcn_exp2f(mrun - mnew);
      mrun = mnew;
      lacc *= sca;
#pragma unroll
      for (int f = 0; f < 4; ++f) oacc[f] *= sca;
    }

    float p[16];
#pragma unroll
    for (int st = 0; st < 4; ++st)
#pragma unroll
      for (int r = 0; r < 4; ++r)
        p[st * 4 + r] = __builtin_amdgcn_exp2f(__builtin_fmaf(sc[st][r], cfold, -mrun));

    char* psb = (char*)&Ps[wv][0];
#pragma unroll
    for (int st = 0; st < 4; ++st) {
      uint2 w;
      w.x = cvtpk(p[st * 4 + 0], p[st * 4 + 1]);
      w.y = cvtpk(p[st * 4 + 2], p[st * 4 + 3]);
      int slot = st * 2 + (g >> 1);
      *(uint2*)&psb[rA * 128 + (((slot ^ rx)) << 4) + ((g & 1) << 3)] = w;
    }
    bf16x8 pf0 = *(const bf16x8*)&psb[rA * 128 + ((g ^ rx) << 4)];
    bf16x8 pf1 = *(const bf16x8*)&psb[rA * 128 + (((4 + g) ^ rx) << 4)];

    const u16* vbl = &Vs[buf][0];
    __builtin_amdgcn_s_setprio(1);
#pragma unroll
    for (int f = 0; f < 4; ++f) {
      bf16x8 v0 = *(const bf16x8*)&vbl[(f * 16 + rA) * 64 + ((g ^ rx) << 3)];
      bf16x8 v1 = *(const bf16x8*)&vbl[(f * 16 + rA) * 64 + (((4 + g) ^ rx) << 3)];
      oacc[f] = __builtin_amdgcn_mfma_f32_16x16x32_bf16(v0, pf0, oacc[f], 0, 0, 0);
      oacc[f] = __builtin_amdgcn_mfma_f32_16x16x32_bf16(v1, pf1, oacc[f], 0, 0, 0);
    }
    lacc = __builtin_amdgcn_mfma_f32_16x16x32_bf16(ones, pf0, lacc, 0, 0, 0);
    lacc = __builtin_amdgcn_mfma_f32_16x16x32_bf16(ones, pf1, lacc, 0, 0, 0);
    __builtin_amdgcn_s_setprio(0);
  }

  float linv = 1.0f / lacc[0];
#pragma unroll
  for (int f = 0; f < 4; ++f) {
    uint2 w;
    w.x = cvtpk(oacc[f][0] * linv, oacc[f][1] * linv);
    w.y = cvtpk(oacc[f][2] * linv, oacc[f][3] * linv);
    *(uint2*)&og[((size_t)b * T_ + q0 + rA) * D_ + h * HS_ + f * 16 + g * 4] = w;
  }
}

// ---------------- host launch ----------------
extern "C" void kernel_launch(void* const* d_in, const int* in_sizes, int n_in,
                              void* d_out, int out_size, void* d_ws, size_t ws_size,
                              hipStream_t stream) {
  const float* x   = (const float*)d_in[0];
  const float* Wq  = (const float*)d_in[1];
  const float* bq  = (const float*)d_in[2];
  const float* Wk  = (const float*)d_in[3];
  const float* bk  = (const float*)d_in[4];
  const float* Wv  = (const float*)d_in[5];
  const float* bv  = (const float*)d_in[6];
  const float* Wp  = (const float*)d_in[7];
  const float* bp  = (const float*)d_in[8];
  const float* W1  = (const float*)d_in[9];
  const float* b1  = (const float*)d_in[10];
  const float* W2  = (const float*)d_in[11];
  const float* b2  = (const float*)d_in[12];
  const float* g1  = (const float*)d_in[13];
  const float* be1 = (const float*)d_in[14];
  const float* g2  = (const float*)d_in[15];
  const float* be2 = (const float*)d_in[16];
  float* out = (float*)d_out;

  char* w = (char*)d_ws;
  auto alloc = [&](size_t bytes) { char* p = w; w += (bytes + 255) & ~(size_t)255; return p; };
  const size_t MD = (size_t)MTOT * D_;

  float* h_f    = (float*)alloc(MD * 4);   // now unused (kept for layout stability)
  u16*   h_b    = (u16*)  alloc(MD * 2);
  u16*   wqkv_t = (u16*)  alloc(3 * (size_t)D_ * D_ * 2);
  u16*   wp_t   = (u16*)  alloc((size_t)D_ * D_ * 2);
  u16*   w1_t   = (u16*)  alloc((size_t)D_ * 4 * D_ * 2);
  u16*   w2_t   = (u16*)  alloc((size_t)D_ * 4 * D_ * 2);
  u16*   q_b    = (u16*)  alloc(MD * 2);
  u16*   k_b    = (u16*)  alloc(MD * 2);
  u16*   v_b    = (u16*)  alloc(MD * 2);   // unused as V now, kept: part of ff1_b span
  u16*   vt_b   = (u16*)  alloc(MD * 2);
  u16*   o_b    = (u16*)  alloc(MD * 2);
  float* hat_f  = (float*)alloc(MD * 4);
  u16*   ff1_b  = q_b;            // [4096,4096] bf16 spans q_b..vt_b
  u16*   h2_b   = h_b;
  float* pf0    = hat_f;          // FF2 split-K partial z=0 (hat_f dead after ln2)
  float* pf1    = (float*)h_f;    // partial z=1: h_f (16MB f32) now free
  (void)v_b;

  dim3 blk(256);

  transpose_qkv<<<dim3(2, 32, 48), blk, 0, stream>>>(Wq, Wk, Wv, wqkv_t);
  transpose_rest<<<dim3(9216), blk, 0, stream>>>(Wp, W1, W2, wp_t, w1_t, w2_t);

  // LN1: bf16 output only (GEMM A-operand AND residual)
  ln_kernel<<<dim3(MTOT), blk, 0, stream>>>(x, g1, be1, h_b);

  // QKV: 256x192 tiles -> grid 16x16 = 256 blocks = 1/CU exactly
  gemm256<0><<<dim3(16, 16), dim3(512), 0, stream>>>(h_b, wqkv_t, bq, bk, bv,
      q_b, k_b, vt_b, MTOT, 3072, 1024);

  // attn: QBLK=128, 8 waves, grid 512
  attn_kernel<<<dim3(B_ * H_ * (T_ / 128)), dim3(512), 0, stream>>>(q_b, k_b, vt_b, o_b);

  // proj: TN=64 -> 512 blocks = 2 blocks/CU; residual from h_b (bf16)
  gemm_bt<2, 64><<<dim3(16, 32, 1), blk, 0, stream>>>(o_b, wp_t, bp, h_b, hat_f,
      nullptr, nullptr, MTOT, 1024, 1024, 1024);

  // LN2: bf16 output only
  ln_kernel<<<dim3(MTOT), blk, 0, stream>>>(hat_f, g2, be2, h2_b);

  // FF1: TN=64 -> 2048 blocks, 36KB LDS -> 4 blocks/CU
  gemm_bt<1, 64><<<dim3(64, 32, 1), blk, 0, stream>>>(h2_b, w1_t, b1, nullptr,
      nullptr, nullptr, ff1_b, MTOT, 4096, 1024, 1024);

  // FF2: TN=128 split-K x2 (measured-best): z=0 -> pf0, z=1 -> pf1
  gemm_bt<3, 128><<<dim3(8, 32, 2), blk, 0, stream>>>(ff1_b, w2_t, nullptr, nullptr,
      pf0, pf1, nullptr, MTOT, 1024, 4096, 2048);

  // out = pf0 + pf1 + b2 + h2 (residual from h2_b bf16)
  reduce_ff2<<<dim3(MTOT), blk, 0, stream>>>(pf0, pf1, b2, h2_b, out);
}

// Round 21
// 257.768 us; speedup vs baseline: 1.0343x; 1.0152x over previous
//
#include <hip/hip_runtime.h>
#include <cstdint>
#include <cstddef>

#define B_  2
#define T_  2048
#define D_  1024
#define H_  16
#define HS_ 64
#define MTOT (B_*T_)   // 4096

typedef unsigned short u16;
typedef __attribute__((ext_vector_type(8))) __bf16 bf16x8;
typedef __attribute__((ext_vector_type(4))) float f32x4;

__device__ __forceinline__ u16 f2bf(float f) {
  unsigned int u = __builtin_bit_cast(unsigned int, f);
  u += 0x7fffu + ((u >> 16) & 1u);
  return (u16)(u >> 16);
}

__device__ __forceinline__ float bf2f(u16 h) {
  return __builtin_bit_cast(float, (unsigned)h << 16);
}

__device__ __forceinline__ unsigned cvtpk(float lo, float hi) {
  unsigned r;
  asm("v_cvt_pk_bf16_f32 %0, %1, %2" : "=v"(r) : "v"(lo), "v"(hi));
  return r;
}

__device__ __forceinline__ void gload16(const u16* g, u16* l) {
  __builtin_amdgcn_global_load_lds((const __attribute__((address_space(1))) void*)g,
                                   (__attribute__((address_space(3))) void*)l, 16, 0, 0);
}

// ---------------- QKV weight transpose + fp32->bf16 (3 srcs, one dispatch) --
__global__ __launch_bounds__(256) void transpose_qkv(const float* __restrict__ wq,
                                                     const float* __restrict__ wk,
                                                     const float* __restrict__ wv,
                                                     u16* __restrict__ out) {
  __shared__ float tile[32][33];
  const int R = 1024, C = 64;
  int z = blockIdx.z, sel = z >> 4, zl = z & 15;
  const float* src = (sel == 0 ? wq : (sel == 1 ? wk : wv)) + (size_t)zl * R * C;
  u16* dst = out + (size_t)sel * 1024 * 1024 + (size_t)zl * R * C;
  int c0 = blockIdx.x * 32, r0 = blockIdx.y * 32;
  int tx = threadIdx.x & 31, ty = threadIdx.x >> 5;
#pragma unroll
  for (int k = 0; k < 4; ++k)
    tile[ty + k*8][tx] = src[(size_t)(r0 + ty + k*8) * C + c0 + tx];
  __syncthreads();
#pragma unroll
  for (int k = 0; k < 4; ++k)
    dst[(size_t)(c0 + ty + k*8) * R + r0 + tx] = f2bf(tile[tx][ty + k*8]);
}

// ---------------- Wp/W1/W2 transpose + fp32->bf16, one flat dispatch --------
__global__ __launch_bounds__(256) void transpose_rest(
    const float* __restrict__ Wp, const float* __restrict__ W1,
    const float* __restrict__ W2, u16* __restrict__ wp_t,
    u16* __restrict__ w1_t, u16* __restrict__ w2_t) {
  __shared__ float tile[32][33];
  int f = blockIdx.x;
  const float* src; u16* dst; int R, C, xx, yy;
  if (f < 1024)      { src = Wp; dst = wp_t; R = 1024; C = 1024; xx = f & 31;  yy = f >> 5; }
  else if (f < 5120) { int f2 = f - 1024; src = W1; dst = w1_t; R = 1024; C = 4096; xx = f2 & 127; yy = f2 >> 7; }
  else               { int f2 = f - 5120; src = W2; dst = w2_t; R = 4096; C = 1024; xx = f2 & 31;  yy = f2 >> 5; }
  int c0 = xx * 32, r0 = yy * 32;
  int tx = threadIdx.x & 31, ty = threadIdx.x >> 5;
#pragma unroll
  for (int k = 0; k < 4; ++k)
    tile[ty + k*8][tx] = src[(size_t)(r0 + ty + k*8) * C + c0 + tx];
  __syncthreads();
#pragma unroll
  for (int k = 0; k < 4; ++k)
    dst[(size_t)(c0 + ty + k*8) * R + r0 + tx] = f2bf(tile[tx][ty + k*8]);
}

// ---------------- layernorm: (fp32|bf16) in -> bf16 out --------------------
template<bool BF16IN>
__global__ __launch_bounds__(256) void ln_kernel(const void* __restrict__ xin,
                                                 const float* __restrict__ gg,
                                                 const float* __restrict__ be,
                                                 u16* __restrict__ hb) {
  int row = blockIdx.x;
  int t = threadIdx.x;
  float4 xv;
  if constexpr (BF16IN) {
    ushort4 h4 = *(const ushort4*)&((const u16*)xin)[(size_t)row * D_ + t * 4];
    xv.x = bf2f(h4.x); xv.y = bf2f(h4.y); xv.z = bf2f(h4.z); xv.w = bf2f(h4.w);
  } else {
    xv = *(const float4*)&((const float*)xin)[(size_t)row * D_ + t * 4];
  }
  float s  = xv.x + xv.y + xv.z + xv.w;
  float ss = xv.x*xv.x + xv.y*xv.y + xv.z*xv.z + xv.w*xv.w;
#pragma unroll
  for (int m = 1; m < 64; m <<= 1) { s += __shfl_xor(s, m); ss += __shfl_xor(ss, m); }
  __shared__ float red[8];
  int lane = t & 63, wv = t >> 6;
  if (lane == 0) { red[wv] = s; red[4 + wv] = ss; }
  __syncthreads();
  s  = red[0] + red[1] + red[2] + red[3];
  ss = red[4] + red[5] + red[6] + red[7];
  float mu  = s * (1.0f / D_);
  float var = ss * (1.0f / D_) - mu * mu;
  float rs  = rsqrtf(var + 1e-5f);
  float4 gv = *(const float4*)&gg[t * 4];
  float4 bv = *(const float4*)&be[t * 4];
  float4 hv;
  hv.x = (xv.x - mu) * rs * gv.x + bv.x;
  hv.y = (xv.y - mu) * rs * gv.y + bv.y;
  hv.z = (xv.z - mu) * rs * gv.z + bv.z;
  hv.w = (xv.w - mu) * rs * gv.w + bv.w;
  uint2 pk;
  pk.x = cvtpk(hv.x, hv.y);
  pk.y = cvtpk(hv.z, hv.w);
  *(uint2*)&hb[(size_t)row * D_ + t * 4] = pk;
}

// ---------------- 256x192 bf16 MFMA GEMM (2-phase, 8 waves) — QKV ----------
// Grid 16x16 = 256 blocks = exactly 1/CU. Per wave 128x48 (acc[8][3]).
// EPI 0: Q,K -> bf16 [B,T,D]; V -> [B,H,HS,T] packed uint2.
template<int EPI>
__global__ __launch_bounds__(512, 2) void gemm256(
    const u16* __restrict__ A, const u16* __restrict__ Bt,
    const float* __restrict__ bias0, const float* __restrict__ bias1,
    const float* __restrict__ bias2,
    u16* __restrict__ o0, u16* __restrict__ o1, u16* __restrict__ o2,
    int M, int N, int K) {
  __shared__ __align__(16) u16 As[2][256 * 64];
  __shared__ __align__(16) u16 Bs[2][192 * 64];
  const int tid = threadIdx.x;
  const int lane = tid & 63, w = tid >> 6;
  const int m0 = blockIdx.y * 256, n0 = blockIdx.x * 192;
  const int rA = lane & 15, g = lane >> 4;
  const int wm = (w >> 2) * 128, wn = (w & 3) * 48;
  const int sxa = rA & 7;

  f32x4 acc[8][3] = {};

  auto stage = [&](int t, int bufi) {
#pragma unroll
    for (int i = 0; i < 4; ++i) {              // A: 2048 chunks
      int c = i * 512 + tid;
      int row = c >> 3;
      int ss = (c & 7) ^ (row & 7);
      gload16(A + (size_t)(m0 + row) * K + t * 64 + ss * 8,
              &As[bufi][0] + (size_t)(i * 512 + w * 64) * 8);
    }
#pragma unroll
    for (int i = 0; i < 3; ++i) {              // B: 1536 chunks (192 rows)
      int c = i * 512 + tid;
      int row = c >> 3;
      int ss = (c & 7) ^ (row & 7);
      gload16(Bt + (size_t)(n0 + row) * K + t * 64 + ss * 8,
              &Bs[bufi][0] + (size_t)(i * 512 + w * 64) * 8);
    }
  };

  stage(0, 0);

  const int nk = K >> 6;
  for (int t = 0; t < nk; ++t) {
    __syncthreads();
    const int buf = t & 1;
    if (t + 1 < nk) stage(t + 1, buf ^ 1);

    bf16x8 bfr[3][2];
#pragma unroll
    for (int j = 0; j < 3; ++j) {
      int br = wn + j * 16 + rA;
#pragma unroll
      for (int kk = 0; kk < 2; ++kk)
        bfr[j][kk] = *(const bf16x8*)&Bs[buf][br * 64 + (((kk * 4 + g) ^ sxa) << 3)];
    }
#pragma unroll
    for (int i = 0; i < 8; ++i) {
      int ar = wm + i * 16 + rA;
      bf16x8 a0 = *(const bf16x8*)&As[buf][ar * 64 + ((g ^ sxa) << 3)];
      bf16x8 a1 = *(const bf16x8*)&As[buf][ar * 64 + (((4 + g) ^ sxa) << 3)];
#pragma unroll
      for (int j = 0; j < 3; ++j) {
        acc[i][j] = __builtin_amdgcn_mfma_f32_16x16x32_bf16(a0, bfr[j][0], acc[i][j], 0, 0, 0);
        acc[i][j] = __builtin_amdgcn_mfma_f32_16x16x32_bf16(a1, bfr[j][1], acc[i][j], 0, 0, 0);
      }
    }
  }

#pragma unroll
  for (int i = 0; i < 8; ++i) {
#pragma unroll
    for (int j = 0; j < 3; ++j) {
      int col = n0 + wn + j * 16 + rA;
      int sel = col >> 10, nn = col & 1023;
      int row0 = m0 + wm + i * 16 + g * 4;
      if (sel == 2) {
        // V: write transposed [B,H,HS,T]; 4 fragment rows = 4 consecutive t
        float bb = bias2[nn];
        int bb_ = row0 >> 11, t0 = row0 & 2047;
        uint2 pkv;
        pkv.x = cvtpk(acc[i][j][0] + bb, acc[i][j][1] + bb);
        pkv.y = cvtpk(acc[i][j][2] + bb, acc[i][j][3] + bb);
        *(uint2*)&o2[((size_t)(bb_ * 1024 + nn)) * 2048 + t0] = pkv;
      } else {
        const float* bp = sel == 0 ? bias0 : bias1;
        u16* op = sel == 0 ? o0 : o1;
#pragma unroll
        for (int r = 0; r < 4; ++r)
          op[(size_t)(row0 + r) * 1024 + nn] = f2bf(acc[i][j][r] + bp[nn]);
      }
    }
  }
}

// ---------------- 128xTN bf16 MFMA GEMM (3-buf, depth-2, counted vmcnt(4)) --
// EPI 1: tanh-GELU(v+bias) -> bf16 ob (FF1, TN=64, 4 blk/CU) ;
// EPI 2: v+bias+res(bf16) -> bf16 ob (proj -> hat_b, TN=64) ;
// EPI 3: bf16 split-K partial (FF2, TN=128): z=0 -> ob, z=1 -> ob2.
template<int EPI, int TN>
__global__ __launch_bounds__(256) void gemm_bt(
    const u16* __restrict__ A, const u16* __restrict__ Bt,
    const float* __restrict__ bias0, const u16* __restrict__ resb,
    u16* __restrict__ ob, u16* __restrict__ ob2,
    int M, int N, int K, int kLen) {
  constexpr int NJ = TN / 32;                 // B fragments per wave
  __shared__ __align__(16) u16 As[3][128 * 32];
  __shared__ __align__(16) u16 Bs[3][TN * 32];
  const int tid = threadIdx.x;
  const int lane = tid & 63, wv = tid >> 6;
  const int m0 = blockIdx.y * 128, n0 = blockIdx.x * TN;
  const int kOff = blockIdx.z * kLen;
  const int rA = lane & 15, g = lane >> 4;
  const int wm = (wv >> 1) * 64, wn = (wv & 1) * (TN / 2);
  const int sx = (rA >> 1) & 3;

  f32x4 acc[4][NJ] = {};

  auto stage = [&](int tt, int bufi) {
#pragma unroll
    for (int p = 0; p < 2; ++p) {
      int c = (p * 4 + wv) * 64 + lane;
      int row = c >> 2;
      int s = (c & 3) ^ ((row >> 1) & 3);
      gload16(A + (size_t)(m0 + row) * K + kOff + tt * 32 + s * 8,
              &As[bufi][0] + (size_t)(p * 4 + wv) * 512);
    }
#pragma unroll
    for (int p = 0; p < TN / 64; ++p) {
      int c = (p * 4 + wv) * 64 + lane;
      int row = c >> 2;
      int s = (c & 3) ^ ((row >> 1) & 3);
      gload16(Bt + (size_t)(n0 + row) * K + kOff + tt * 32 + s * 8,
              &Bs[bufi][0] + (size_t)(p * 4 + wv) * 512);
    }
  };

  const int nk = kLen >> 5;
  stage(0, 0);
  stage(1, 1);

  int cur = 0, nxt = 2;
  for (int t = 0; t < nk; ++t) {
    if (t + 1 < nk) asm volatile("s_waitcnt vmcnt(4)" ::: "memory");
    else            asm volatile("s_waitcnt vmcnt(0)" ::: "memory");
    __builtin_amdgcn_s_barrier();
    __builtin_amdgcn_sched_barrier(0);
    if (t + 2 < nk) stage(t + 2, nxt);

    bf16x8 a[4], b[NJ];
#pragma unroll
    for (int i = 0; i < 4; ++i)
      a[i] = *(const bf16x8*)&As[cur][(wm + i * 16 + rA) * 32 + ((g ^ sx) << 3)];
#pragma unroll
    for (int j = 0; j < NJ; ++j)
      b[j] = *(const bf16x8*)&Bs[cur][(wn + j * 16 + rA) * 32 + ((g ^ sx) << 3)];
#pragma unroll
    for (int i = 0; i < 4; ++i)
#pragma unroll
      for (int j = 0; j < NJ; ++j)
        acc[i][j] = __builtin_amdgcn_mfma_f32_16x16x32_bf16(a[i], b[j], acc[i][j], 0, 0, 0);

    cur = (cur == 2) ? 0 : cur + 1;
    nxt = (nxt == 2) ? 0 : nxt + 1;
  }

#pragma unroll
  for (int i = 0; i < 4; ++i) {
#pragma unroll
    for (int j = 0; j < NJ; ++j) {
#pragma unroll
      for (int r = 0; r < 4; ++r) {
        int row = m0 + wm + i * 16 + g * 4 + r;
        int col = n0 + wn + j * 16 + rA;
        float v = acc[i][j][r];
        if constexpr (EPI == 1) {
          v += bias0[col];
          float z = 0.7978845608f * (v + 0.044715f * v * v * v);
          z = fminf(z, 18.0f);
          float e = __builtin_amdgcn_exp2f(z * 2.8853900817779268f);
          v = v * e / (e + 1.0f);
          ob[(size_t)row * N + col] = f2bf(v);
        } else if constexpr (EPI == 2) {
          v += bias0[col] + bf2f(resb[(size_t)row * N + col]);
          ob[(size_t)row * N + col] = f2bf(v);
        } else {
          u16* dst = blockIdx.z ? ob2 : ob;
          dst[(size_t)row * N + col] = f2bf(v);
        }
      }
    }
  }
}

// out = p0 + p1 + bias[col] + res  (all bf16 except bias/out; N=1024)
__global__ __launch_bounds__(256) void reduce_ff2(const u16* __restrict__ p0,
                                                  const u16* __restrict__ p1,
                                                  const float* __restrict__ bias,
                                                  const u16* __restrict__ resb,
                                                  float* __restrict__ out) {
  int i = (blockIdx.x * 256 + threadIdx.x) * 4;
  ushort4 a = *(const ushort4*)&p0[i];
  ushort4 b = *(const ushort4*)&p1[i];
  ushort4 hv = *(const ushort4*)&resb[i];
  float4 bb = *(const float4*)&bias[i & 1023];
  float4 o;
  o.x = bf2f(a.x) + bf2f(b.x) + bf2f(hv.x) + bb.x;
  o.y = bf2f(a.y) + bf2f(b.y) + bf2f(hv.y) + bb.y;
  o.z = bf2f(a.z) + bf2f(b.z) + bf2f(hv.z) + bb.z;
  o.w = bf2f(a.w) + bf2f(b.w) + bf2f(hv.w) + bb.w;
  *(float4*)&out[i] = o;
}

// ---------------- flash attention (QBLK=128, 8 waves, swapped QK^T) --------
__global__ __launch_bounds__(512) void attn_kernel(const u16* __restrict__ qg,
                                                   const u16* __restrict__ kg,
                                                   const u16* __restrict__ vtg,
                                                   u16* __restrict__ og) {
  const int wg = blockIdx.x;
  const int qt = wg & 15;            // 16 q-tiles of 128 rows
  const int h  = (wg >> 4) & 15;
  const int b  = wg >> 8;
  const int tid = threadIdx.x, lane = tid & 63, wv = tid >> 6;
  const int q0 = qt * 128 + wv * 16;
  const int rA = lane & 15, g = lane >> 4;
  const int rx = rA & 7;

  __shared__ __align__(16) u16 Ks[2][64 * 64];   // [key][dim]
  __shared__ __align__(16) u16 Vs[2][64 * 64];   // [hs][key]
  __shared__ __align__(16) u16 Ps[8][16 * 64];   // per-wave P^T

  const size_t qoff = ((size_t)b * T_ + q0 + rA) * D_ + h * HS_ + g * 8;
  const bf16x8 aq0 = *(const bf16x8*)&qg[qoff];
  const bf16x8 aq1 = *(const bf16x8*)&qg[qoff + 32];

  const u16* kbase = kg + (size_t)b * T_ * D_ + h * HS_;
  const u16* vbase = vtg + ((size_t)b * H_ + h) * HS_ * T_;

  const float cfold = 0.18033688011112042f;  // HS^-0.5 * log2(e)
  float mrun = -1e30f;
  f32x4 oacc[4] = {};
  f32x4 lacc = {};
  bf16x8 ones;
#pragma unroll
  for (int e = 0; e < 8; ++e) ones[e] = (__bf16)1.0f;

  auto stage = [&](int t, int buf) {
    int row = tid >> 3, s = tid & 7;
    int ss = s ^ (row & 7);
    gload16(kbase + ((size_t)t * 64 + row) * D_ + ss * 8,
            &Ks[buf][0] + (size_t)(wv * 64) * 8);
    gload16(vbase + (size_t)row * T_ + t * 64 + ss * 8,
            &Vs[buf][0] + (size_t)(wv * 64) * 8);
  };

  stage(0, 0);

  const int NT = T_ / 64;
  for (int t = 0; t < NT; ++t) {
    __syncthreads();
    const int buf = t & 1;
    if (t + 1 < NT) stage(t + 1, buf ^ 1);

    const u16* kb = &Ks[buf][0];
    f32x4 sc[4];
    __builtin_amdgcn_s_setprio(1);
#pragma unroll
    for (int st = 0; st < 4; ++st) {
      bf16x8 k0 = *(const bf16x8*)&kb[(st * 16 + rA) * 64 + ((g ^ rx) << 3)];
      bf16x8 k1 = *(const bf16x8*)&kb[(st * 16 + rA) * 64 + (((4 + g) ^ rx) << 3)];
      f32x4 z = {};
      z = __builtin_amdgcn_mfma_f32_16x16x32_bf16(k0, aq0, z, 0, 0, 0);
      z = __builtin_amdgcn_mfma_f32_16x16x32_bf16(k1, aq1, z, 0, 0, 0);
      sc[st] = z;
    }
    __builtin_amdgcn_s_setprio(0);

    float a0 = fmaxf(fmaxf(sc[0][0], sc[0][1]), fmaxf(sc[0][2], sc[0][3]));
    float a1 = fmaxf(fmaxf(sc[1][0], sc[1][1]), fmaxf(sc[1][2], sc[1][3]));
    float a2 = fmaxf(fmaxf(sc[2][0], sc[2][1]), fmaxf(sc[2][2], sc[2][3]));
    float a3 = fmaxf(fmaxf(sc[3][0], sc[3][1]), fmaxf(sc[3][2], sc[3][3]));
    float mx = fmaxf(fmaxf(a0, a1), fmaxf(a2, a3));
    mx = fmaxf(mx, __shfl_xor(mx, 16));
    mx = fmaxf(mx, __shfl_xor(mx, 32));
    float tm = mx * cfold;

    if (__any(tm > mrun + 8.0f)) {           // defer-max (T13)
      float mnew = fmaxf(mrun, tm);
      float sca = __builtin_amdgcn_exp2f(mrun - mnew);
      mrun = mnew;
      lacc *= sca;
#pragma unroll
      for (int f = 0; f < 4; ++f) oacc[f] *= sca;
    }

    float p[16];
#pragma unroll
    for (int st = 0; st < 4; ++st)
#pragma unroll
      for (int r = 0; r < 4; ++r)
        p[st * 4 + r] = __builtin_amdgcn_exp2f(__builtin_fmaf(sc[st][r], cfold, -mrun));

    char* psb = (char*)&Ps[wv][0];
#pragma unroll
    for (int st = 0; st < 4; ++st) {
      uint2 w;
      w.x = cvtpk(p[st * 4 + 0], p[st * 4 + 1]);
      w.y = cvtpk(p[st * 4 + 2], p[st * 4 + 3]);
      int slot = st * 2 + (g >> 1);
      *(uint2*)&psb[rA * 128 + (((slot ^ rx)) << 4) + ((g & 1) << 3)] = w;
    }
    bf16x8 pf0 = *(const bf16x8*)&psb[rA * 128 + ((g ^ rx) << 4)];
    bf16x8 pf1 = *(const bf16x8*)&psb[rA * 128 + (((4 + g) ^ rx) << 4)];

    const u16* vbl = &Vs[buf][0];
    __builtin_amdgcn_s_setprio(1);
#pragma unroll
    for (int f = 0; f < 4; ++f) {
      bf16x8 v0 = *(const bf16x8*)&vbl[(f * 16 + rA) * 64 + ((g ^ rx) << 3)];
      bf16x8 v1 = *(const bf16x8*)&vbl[(f * 16 + rA) * 64 + (((4 + g) ^ rx) << 3)];
      oacc[f] = __builtin_amdgcn_mfma_f32_16x16x32_bf16(v0, pf0, oacc[f], 0, 0, 0);
      oacc[f] = __builtin_amdgcn_mfma_f32_16x16x32_bf16(v1, pf1, oacc[f], 0, 0, 0);
    }
    lacc = __builtin_amdgcn_mfma_f32_16x16x32_bf16(ones, pf0, lacc, 0, 0, 0);
    lacc = __builtin_amdgcn_mfma_f32_16x16x32_bf16(ones, pf1, lacc, 0, 0, 0);
    __builtin_amdgcn_s_setprio(0);
  }

  float linv = 1.0f / lacc[0];
#pragma unroll
  for (int f = 0; f < 4; ++f) {
    uint2 w;
    w.x = cvtpk(oacc[f][0] * linv, oacc[f][1] * linv);
    w.y = cvtpk(oacc[f][2] * linv, oacc[f][3] * linv);
    *(uint2*)&og[((size_t)b * T_ + q0 + rA) * D_ + h * HS_ + f * 16 + g * 4] = w;
  }
}

// ---------------- host launch ----------------
extern "C" void kernel_launch(void* const* d_in, const int* in_sizes, int n_in,
                              void* d_out, int out_size, void* d_ws, size_t ws_size,
                              hipStream_t stream) {
  const float* x   = (const float*)d_in[0];
  const float* Wq  = (const float*)d_in[1];
  const float* bq  = (const float*)d_in[2];
  const float* Wk  = (const float*)d_in[3];
  const float* bk  = (const float*)d_in[4];
  const float* Wv  = (const float*)d_in[5];
  const float* bv  = (const float*)d_in[6];
  const float* Wp  = (const float*)d_in[7];
  const float* bp  = (const float*)d_in[8];
  const float* W1  = (const float*)d_in[9];
  const float* b1  = (const float*)d_in[10];
  const float* W2  = (const float*)d_in[11];
  const float* b2  = (const float*)d_in[12];
  const float* g1  = (const float*)d_in[13];
  const float* be1 = (const float*)d_in[14];
  const float* g2  = (const float*)d_in[15];
  const float* be2 = (const float*)d_in[16];
  float* out = (float*)d_out;

  char* w = (char*)d_ws;
  auto alloc = [&](size_t bytes) { char* p = w; w += (bytes + 255) & ~(size_t)255; return p; };
  const size_t MD = (size_t)MTOT * D_;

  float* h_f    = (float*)alloc(MD * 4);   // region reused: hat_b (bf16)
  u16*   h_b    = (u16*)  alloc(MD * 2);
  u16*   wqkv_t = (u16*)  alloc(3 * (size_t)D_ * D_ * 2);
  u16*   wp_t   = (u16*)  alloc((size_t)D_ * D_ * 2);
  u16*   w1_t   = (u16*)  alloc((size_t)D_ * 4 * D_ * 2);
  u16*   w2_t   = (u16*)  alloc((size_t)D_ * 4 * D_ * 2);
  u16*   q_b    = (u16*)  alloc(MD * 2);
  u16*   k_b    = (u16*)  alloc(MD * 2);
  u16*   v_b    = (u16*)  alloc(MD * 2);   // unused as V now, kept: part of ff1_b span
  u16*   vt_b   = (u16*)  alloc(MD * 2);
  u16*   o_b    = (u16*)  alloc(MD * 2);
  float* hat_f  = (float*)alloc(MD * 4);   // region reused: pb0/pb1 (bf16)
  u16*   ff1_b  = q_b;            // [4096,4096] bf16 spans q_b..vt_b
  u16*   h2_b   = h_b;
  u16*   hat_b  = (u16*)h_f;      // proj output, bf16 (h_f region free)
  u16*   pb0    = (u16*)hat_f;            // FF2 split-K partial z=0 (bf16)
  u16*   pb1    = (u16*)hat_f + MD;       // FF2 split-K partial z=1 (bf16)
  (void)v_b;

  dim3 blk(256);

  transpose_qkv<<<dim3(2, 32, 48), blk, 0, stream>>>(Wq, Wk, Wv, wqkv_t);
  transpose_rest<<<dim3(9216), blk, 0, stream>>>(Wp, W1, W2, wp_t, w1_t, w2_t);

  // LN1: f32 in -> bf16 out (GEMM A-operand AND residual)
  ln_kernel<false><<<dim3(MTOT), blk, 0, stream>>>(x, g1, be1, h_b);

  // QKV: 256x192 tiles -> grid 16x16 = 256 blocks = 1/CU exactly
  gemm256<0><<<dim3(16, 16), dim3(512), 0, stream>>>(h_b, wqkv_t, bq, bk, bv,
      q_b, k_b, vt_b, MTOT, 3072, 1024);

  // attn: QBLK=128, 8 waves, grid 512
  attn_kernel<<<dim3(B_ * H_ * (T_ / 128)), dim3(512), 0, stream>>>(q_b, k_b, vt_b, o_b);

  // proj: TN=64; residual h_b (bf16); writes hat_b (bf16)
  gemm_bt<2, 64><<<dim3(16, 32, 1), blk, 0, stream>>>(o_b, wp_t, bp, h_b,
      hat_b, nullptr, MTOT, 1024, 1024, 1024);

  // LN2: bf16 in -> bf16 out
  ln_kernel<true><<<dim3(MTOT), blk, 0, stream>>>(hat_b, g2, be2, h2_b);

  // FF1: TN=64 -> 2048 blocks, 36KB LDS -> 4 blocks/CU
  gemm_bt<1, 64><<<dim3(64, 32, 1), blk, 0, stream>>>(h2_b, w1_t, b1, nullptr,
      ff1_b, nullptr, MTOT, 4096, 1024, 1024);

  // FF2: TN=128 split-K x2; bf16 partials: z=0 -> pb0, z=1 -> pb1
  gemm_bt<3, 128><<<dim3(8, 32, 2), blk, 0, stream>>>(ff1_b, w2_t, nullptr, nullptr,
      pb0, pb1, MTOT, 1024, 4096, 2048);

  // out = pb0 + pb1 + b2 + h2 (f32 out)
  reduce_ff2<<<dim3(MTOT), blk, 0, stream>>>(pb0, pb1, b2, h2_b, out);
}

// Round 22
// 253.246 us; speedup vs baseline: 1.0528x; 1.0179x over previous
//
#include <hip/hip_runtime.h>
#include <cstdint>
#include <cstddef>

#define B_  2
#define T_  2048
#define D_  1024
#define H_  16
#define HS_ 64
#define MTOT (B_*T_)   // 4096

typedef unsigned short u16;
typedef __attribute__((ext_vector_type(8))) __bf16 bf16x8;
typedef __attribute__((ext_vector_type(4))) float f32x4;

__device__ __forceinline__ u16 f2bf(float f) {
  unsigned int u = __builtin_bit_cast(unsigned int, f);
  u += 0x7fffu + ((u >> 16) & 1u);
  return (u16)(u >> 16);
}

__device__ __forceinline__ float bf2f(u16 h) {
  return __builtin_bit_cast(float, (unsigned)h << 16);
}

__device__ __forceinline__ unsigned cvtpk(float lo, float hi) {
  unsigned r;
  asm("v_cvt_pk_bf16_f32 %0, %1, %2" : "=v"(r) : "v"(lo), "v"(hi));
  return r;
}

__device__ __forceinline__ void gload16(const u16* g, u16* l) {
  __builtin_amdgcn_global_load_lds((const __attribute__((address_space(1))) void*)g,
                                   (__attribute__((address_space(3))) void*)l, 16, 0, 0);
}

// ---------------- fused prologue: all weight transposes + LN1 --------------
// Blocks 0..3071:      Wq/Wk/Wv transpose (fp32 -> bf16 B^T)
// Blocks 3072..12287:  Wp/W1/W2 transpose
// Blocks 12288..16383: LN1 (x fp32 -> h_b bf16)
// All three roles are data-independent; branch is blockIdx-uniform.
__global__ __launch_bounds__(256) void prologue(
    const float* __restrict__ wq, const float* __restrict__ wk,
    const float* __restrict__ wv, u16* __restrict__ wqkv_t,
    const float* __restrict__ Wp, const float* __restrict__ W1,
    const float* __restrict__ W2, u16* __restrict__ wp_t,
    u16* __restrict__ w1_t, u16* __restrict__ w2_t,
    const float* __restrict__ x, const float* __restrict__ g1,
    const float* __restrict__ be1, u16* __restrict__ hb) {
  int f = blockIdx.x;
  int t = threadIdx.x;

  if (f >= 12288) {
    // ---- LN1 role ----
    int row = f - 12288;
    float4 xv = *(const float4*)&x[(size_t)row * D_ + t * 4];
    float s  = xv.x + xv.y + xv.z + xv.w;
    float ss = xv.x*xv.x + xv.y*xv.y + xv.z*xv.z + xv.w*xv.w;
#pragma unroll
    for (int m = 1; m < 64; m <<= 1) { s += __shfl_xor(s, m); ss += __shfl_xor(ss, m); }
    __shared__ float red[8];
    int lane = t & 63, wv_ = t >> 6;
    if (lane == 0) { red[wv_] = s; red[4 + wv_] = ss; }
    __syncthreads();
    s  = red[0] + red[1] + red[2] + red[3];
    ss = red[4] + red[5] + red[6] + red[7];
    float mu  = s * (1.0f / D_);
    float var = ss * (1.0f / D_) - mu * mu;
    float rs  = rsqrtf(var + 1e-5f);
    float4 gv = *(const float4*)&g1[t * 4];
    float4 bv = *(const float4*)&be1[t * 4];
    float4 hv;
    hv.x = (xv.x - mu) * rs * gv.x + bv.x;
    hv.y = (xv.y - mu) * rs * gv.y + bv.y;
    hv.z = (xv.z - mu) * rs * gv.z + bv.z;
    hv.w = (xv.w - mu) * rs * gv.w + bv.w;
    uint2 pk;
    pk.x = cvtpk(hv.x, hv.y);
    pk.y = cvtpk(hv.z, hv.w);
    *(uint2*)&hb[(size_t)row * D_ + t * 4] = pk;
    return;
  }

  // ---- transpose role ----
  __shared__ float tile[32][33];
  const float* src; u16* dst; int R, C, c0, r0;
  if (f < 3072) {
    int z = f >> 6, rem = f & 63, yy = rem >> 1, xx = rem & 1;
    int sel = z >> 4, zl = z & 15;
    src = (sel == 0 ? wq : (sel == 1 ? wk : wv)) + (size_t)zl * 1024 * 64;
    dst = wqkv_t + (size_t)sel * 1024 * 1024 + (size_t)zl * 1024 * 64;
    R = 1024; C = 64; c0 = xx * 32; r0 = yy * 32;
  } else {
    int f2 = f - 3072;
    if (f2 < 1024)      { src = Wp; dst = wp_t; R = 1024; C = 1024; c0 = (f2 & 31) * 32;  r0 = (f2 >> 5) * 32; }
    else if (f2 < 5120) { int f3 = f2 - 1024; src = W1; dst = w1_t; R = 1024; C = 4096; c0 = (f3 & 127) * 32; r0 = (f3 >> 7) * 32; }
    else                { int f3 = f2 - 5120; src = W2; dst = w2_t; R = 4096; C = 1024; c0 = (f3 & 31) * 32;  r0 = (f3 >> 5) * 32; }
  }
  int tx = t & 31, ty = t >> 5;
#pragma unroll
  for (int k = 0; k < 4; ++k)
    tile[ty + k*8][tx] = src[(size_t)(r0 + ty + k*8) * C + c0 + tx];
  __syncthreads();
#pragma unroll
  for (int k = 0; k < 4; ++k)
    dst[(size_t)(c0 + ty + k*8) * R + r0 + tx] = f2bf(tile[tx][ty + k*8]);
}

// ---------------- layernorm: bf16 in -> bf16 out (LN2) ---------------------
__global__ __launch_bounds__(256) void ln_kernel_b(const u16* __restrict__ xin,
                                                   const float* __restrict__ gg,
                                                   const float* __restrict__ be,
                                                   u16* __restrict__ hb) {
  int row = blockIdx.x;
  int t = threadIdx.x;
  ushort4 h4 = *(const ushort4*)&xin[(size_t)row * D_ + t * 4];
  float4 xv;
  xv.x = bf2f(h4.x); xv.y = bf2f(h4.y); xv.z = bf2f(h4.z); xv.w = bf2f(h4.w);
  float s  = xv.x + xv.y + xv.z + xv.w;
  float ss = xv.x*xv.x + xv.y*xv.y + xv.z*xv.z + xv.w*xv.w;
#pragma unroll
  for (int m = 1; m < 64; m <<= 1) { s += __shfl_xor(s, m); ss += __shfl_xor(ss, m); }
  __shared__ float red[8];
  int lane = t & 63, wv = t >> 6;
  if (lane == 0) { red[wv] = s; red[4 + wv] = ss; }
  __syncthreads();
  s  = red[0] + red[1] + red[2] + red[3];
  ss = red[4] + red[5] + red[6] + red[7];
  float mu  = s * (1.0f / D_);
  float var = ss * (1.0f / D_) - mu * mu;
  float rs  = rsqrtf(var + 1e-5f);
  float4 gv = *(const float4*)&gg[t * 4];
  float4 bv = *(const float4*)&be[t * 4];
  float4 hv;
  hv.x = (xv.x - mu) * rs * gv.x + bv.x;
  hv.y = (xv.y - mu) * rs * gv.y + bv.y;
  hv.z = (xv.z - mu) * rs * gv.z + bv.z;
  hv.w = (xv.w - mu) * rs * gv.w + bv.w;
  uint2 pk;
  pk.x = cvtpk(hv.x, hv.y);
  pk.y = cvtpk(hv.z, hv.w);
  *(uint2*)&hb[(size_t)row * D_ + t * 4] = pk;
}

// ---------------- 256x192 bf16 MFMA GEMM (2-phase, 8 waves) — QKV ----------
// Grid 16x16 = 256 blocks = exactly 1/CU. Per wave 128x48 (acc[8][3]).
// EPI 0: Q,K -> bf16 [B,T,D]; V -> [B,H,HS,T] packed uint2.
template<int EPI>
__global__ __launch_bounds__(512, 2) void gemm256(
    const u16* __restrict__ A, const u16* __restrict__ Bt,
    const float* __restrict__ bias0, const float* __restrict__ bias1,
    const float* __restrict__ bias2,
    u16* __restrict__ o0, u16* __restrict__ o1, u16* __restrict__ o2,
    int M, int N, int K) {
  __shared__ __align__(16) u16 As[2][256 * 64];
  __shared__ __align__(16) u16 Bs[2][192 * 64];
  const int tid = threadIdx.x;
  const int lane = tid & 63, w = tid >> 6;
  const int m0 = blockIdx.y * 256, n0 = blockIdx.x * 192;
  const int rA = lane & 15, g = lane >> 4;
  const int wm = (w >> 2) * 128, wn = (w & 3) * 48;
  const int sxa = rA & 7;

  f32x4 acc[8][3] = {};

  auto stage = [&](int t, int bufi) {
#pragma unroll
    for (int i = 0; i < 4; ++i) {              // A: 2048 chunks
      int c = i * 512 + tid;
      int row = c >> 3;
      int ss = (c & 7) ^ (row & 7);
      gload16(A + (size_t)(m0 + row) * K + t * 64 + ss * 8,
              &As[bufi][0] + (size_t)(i * 512 + w * 64) * 8);
    }
#pragma unroll
    for (int i = 0; i < 3; ++i) {              // B: 1536 chunks (192 rows)
      int c = i * 512 + tid;
      int row = c >> 3;
      int ss = (c & 7) ^ (row & 7);
      gload16(Bt + (size_t)(n0 + row) * K + t * 64 + ss * 8,
              &Bs[bufi][0] + (size_t)(i * 512 + w * 64) * 8);
    }
  };

  stage(0, 0);

  const int nk = K >> 6;
  for (int t = 0; t < nk; ++t) {
    __syncthreads();
    const int buf = t & 1;
    if (t + 1 < nk) stage(t + 1, buf ^ 1);

    bf16x8 bfr[3][2];
#pragma unroll
    for (int j = 0; j < 3; ++j) {
      int br = wn + j * 16 + rA;
#pragma unroll
      for (int kk = 0; kk < 2; ++kk)
        bfr[j][kk] = *(const bf16x8*)&Bs[buf][br * 64 + (((kk * 4 + g) ^ sxa) << 3)];
    }
#pragma unroll
    for (int i = 0; i < 8; ++i) {
      int ar = wm + i * 16 + rA;
      bf16x8 a0 = *(const bf16x8*)&As[buf][ar * 64 + ((g ^ sxa) << 3)];
      bf16x8 a1 = *(const bf16x8*)&As[buf][ar * 64 + (((4 + g) ^ sxa) << 3)];
#pragma unroll
      for (int j = 0; j < 3; ++j) {
        acc[i][j] = __builtin_amdgcn_mfma_f32_16x16x32_bf16(a0, bfr[j][0], acc[i][j], 0, 0, 0);
        acc[i][j] = __builtin_amdgcn_mfma_f32_16x16x32_bf16(a1, bfr[j][1], acc[i][j], 0, 0, 0);
      }
    }
  }

#pragma unroll
  for (int i = 0; i < 8; ++i) {
#pragma unroll
    for (int j = 0; j < 3; ++j) {
      int col = n0 + wn + j * 16 + rA;
      int sel = col >> 10, nn = col & 1023;
      int row0 = m0 + wm + i * 16 + g * 4;
      if (sel == 2) {
        // V: write transposed [B,H,HS,T]; 4 fragment rows = 4 consecutive t
        float bb = bias2[nn];
        int bb_ = row0 >> 11, t0 = row0 & 2047;
        uint2 pkv;
        pkv.x = cvtpk(acc[i][j][0] + bb, acc[i][j][1] + bb);
        pkv.y = cvtpk(acc[i][j][2] + bb, acc[i][j][3] + bb);
        *(uint2*)&o2[((size_t)(bb_ * 1024 + nn)) * 2048 + t0] = pkv;
      } else {
        const float* bp = sel == 0 ? bias0 : bias1;
        u16* op = sel == 0 ? o0 : o1;
#pragma unroll
        for (int r = 0; r < 4; ++r)
          op[(size_t)(row0 + r) * 1024 + nn] = f2bf(acc[i][j][r] + bp[nn]);
      }
    }
  }
}

// ---------------- 128xTN bf16 MFMA GEMM (3-buf, depth-2, counted vmcnt(4)) --
// EPI 1: tanh-GELU(v+bias) -> bf16 ob (FF1, TN=64, 4 blk/CU) ;
// EPI 2: v+bias+res(bf16) -> bf16 ob (proj -> hat_b, TN=64) ;
// EPI 3: bf16 split-K partial (FF2, TN=128): z=0 -> ob, z=1 -> ob2.
template<int EPI, int TN>
__global__ __launch_bounds__(256) void gemm_bt(
    const u16* __restrict__ A, const u16* __restrict__ Bt,
    const float* __restrict__ bias0, const u16* __restrict__ resb,
    u16* __restrict__ ob, u16* __restrict__ ob2,
    int M, int N, int K, int kLen) {
  constexpr int NJ = TN / 32;                 // B fragments per wave
  __shared__ __align__(16) u16 As[3][128 * 32];
  __shared__ __align__(16) u16 Bs[3][TN * 32];
  const int tid = threadIdx.x;
  const int lane = tid & 63, wv = tid >> 6;
  const int m0 = blockIdx.y * 128, n0 = blockIdx.x * TN;
  const int kOff = blockIdx.z * kLen;
  const int rA = lane & 15, g = lane >> 4;
  const int wm = (wv >> 1) * 64, wn = (wv & 1) * (TN / 2);
  const int sx = (rA >> 1) & 3;

  f32x4 acc[4][NJ] = {};

  auto stage = [&](int tt, int bufi) {
#pragma unroll
    for (int p = 0; p < 2; ++p) {
      int c = (p * 4 + wv) * 64 + lane;
      int row = c >> 2;
      int s = (c & 3) ^ ((row >> 1) & 3);
      gload16(A + (size_t)(m0 + row) * K + kOff + tt * 32 + s * 8,
              &As[bufi][0] + (size_t)(p * 4 + wv) * 512);
    }
#pragma unroll
    for (int p = 0; p < TN / 64; ++p) {
      int c = (p * 4 + wv) * 64 + lane;
      int row = c >> 2;
      int s = (c & 3) ^ ((row >> 1) & 3);
      gload16(Bt + (size_t)(n0 + row) * K + kOff + tt * 32 + s * 8,
              &Bs[bufi][0] + (size_t)(p * 4 + wv) * 512);
    }
  };

  const int nk = kLen >> 5;
  stage(0, 0);
  stage(1, 1);

  int cur = 0, nxt = 2;
  for (int t = 0; t < nk; ++t) {
    if (t + 1 < nk) asm volatile("s_waitcnt vmcnt(4)" ::: "memory");
    else            asm volatile("s_waitcnt vmcnt(0)" ::: "memory");
    __builtin_amdgcn_s_barrier();
    __builtin_amdgcn_sched_barrier(0);
    if (t + 2 < nk) stage(t + 2, nxt);

    bf16x8 a[4], b[NJ];
#pragma unroll
    for (int i = 0; i < 4; ++i)
      a[i] = *(const bf16x8*)&As[cur][(wm + i * 16 + rA) * 32 + ((g ^ sx) << 3)];
#pragma unroll
    for (int j = 0; j < NJ; ++j)
      b[j] = *(const bf16x8*)&Bs[cur][(wn + j * 16 + rA) * 32 + ((g ^ sx) << 3)];
#pragma unroll
    for (int i = 0; i < 4; ++i)
#pragma unroll
      for (int j = 0; j < NJ; ++j)
        acc[i][j] = __builtin_amdgcn_mfma_f32_16x16x32_bf16(a[i], b[j], acc[i][j], 0, 0, 0);

    cur = (cur == 2) ? 0 : cur + 1;
    nxt = (nxt == 2) ? 0 : nxt + 1;
  }

#pragma unroll
  for (int i = 0; i < 4; ++i) {
#pragma unroll
    for (int j = 0; j < NJ; ++j) {
#pragma unroll
      for (int r = 0; r < 4; ++r) {
        int row = m0 + wm + i * 16 + g * 4 + r;
        int col = n0 + wn + j * 16 + rA;
        float v = acc[i][j][r];
        if constexpr (EPI == 1) {
          v += bias0[col];
          float z = 0.7978845608f * (v + 0.044715f * v * v * v);
          z = fminf(z, 18.0f);
          float e = __builtin_amdgcn_exp2f(z * 2.8853900817779268f);
          v = v * e / (e + 1.0f);
          ob[(size_t)row * N + col] = f2bf(v);
        } else if constexpr (EPI == 2) {
          v += bias0[col] + bf2f(resb[(size_t)row * N + col]);
          ob[(size_t)row * N + col] = f2bf(v);
        } else {
          u16* dst = blockIdx.z ? ob2 : ob;
          dst[(size_t)row * N + col] = f2bf(v);
        }
      }
    }
  }
}

// out = p0 + p1 + bias[col] + res  (all bf16 except bias/out; N=1024)
__global__ __launch_bounds__(256) void reduce_ff2(const u16* __restrict__ p0,
                                                  const u16* __restrict__ p1,
                                                  const float* __restrict__ bias,
                                                  const u16* __restrict__ resb,
                                                  float* __restrict__ out) {
  int i = (blockIdx.x * 256 + threadIdx.x) * 4;
  ushort4 a = *(const ushort4*)&p0[i];
  ushort4 b = *(const ushort4*)&p1[i];
  ushort4 hv = *(const ushort4*)&resb[i];
  float4 bb = *(const float4*)&bias[i & 1023];
  float4 o;
  o.x = bf2f(a.x) + bf2f(b.x) + bf2f(hv.x) + bb.x;
  o.y = bf2f(a.y) + bf2f(b.y) + bf2f(hv.y) + bb.y;
  o.z = bf2f(a.z) + bf2f(b.z) + bf2f(hv.z) + bb.z;
  o.w = bf2f(a.w) + bf2f(b.w) + bf2f(hv.w) + bb.w;
  *(float4*)&out[i] = o;
}

// ---------------- flash attention (QBLK=128, 8 waves, swapped QK^T) --------
__global__ __launch_bounds__(512) void attn_kernel(const u16* __restrict__ qg,
                                                   const u16* __restrict__ kg,
                                                   const u16* __restrict__ vtg,
                                                   u16* __restrict__ og) {
  const int wg = blockIdx.x;
  const int qt = wg & 15;            // 16 q-tiles of 128 rows
  const int h  = (wg >> 4) & 15;
  const int b  = wg >> 8;
  const int tid = threadIdx.x, lane = tid & 63, wv = tid >> 6;
  const int q0 = qt * 128 + wv * 16;
  const int rA = lane & 15, g = lane >> 4;
  const int rx = rA & 7;

  __shared__ __align__(16) u16 Ks[2][64 * 64];   // [key][dim]
  __shared__ __align__(16) u16 Vs[2][64 * 64];   // [hs][key]
  __shared__ __align__(16) u16 Ps[8][16 * 64];   // per-wave P^T

  const size_t qoff = ((size_t)b * T_ + q0 + rA) * D_ + h * HS_ + g * 8;
  const bf16x8 aq0 = *(const bf16x8*)&qg[qoff];
  const bf16x8 aq1 = *(const bf16x8*)&qg[qoff + 32];

  const u16* kbase = kg + (size_t)b * T_ * D_ + h * HS_;
  const u16* vbase = vtg + ((size_t)b * H_ + h) * HS_ * T_;

  const float cfold = 0.18033688011112042f;  // HS^-0.5 * log2(e)
  float mrun = -1e30f;
  f32x4 oacc[4] = {};
  f32x4 lacc = {};
  bf16x8 ones;
#pragma unroll
  for (int e = 0; e < 8; ++e) ones[e] = (__bf16)1.0f;

  auto stage = [&](int t, int buf) {
    int row = tid >> 3, s = tid & 7;
    int ss = s ^ (row & 7);
    gload16(kbase + ((size_t)t * 64 + row) * D_ + ss * 8,
            &Ks[buf][0] + (size_t)(wv * 64) * 8);
    gload16(vbase + (size_t)row * T_ + t * 64 + ss * 8,
            &Vs[buf][0] + (size_t)(wv * 64) * 8);
  };

  stage(0, 0);

  const int NT = T_ / 64;
  for (int t = 0; t < NT; ++t) {
    __syncthreads();
    const int buf = t & 1;
    if (t + 1 < NT) stage(t + 1, buf ^ 1);

    const u16* kb = &Ks[buf][0];
    f32x4 sc[4];
    __builtin_amdgcn_s_setprio(1);
#pragma unroll
    for (int st = 0; st < 4; ++st) {
      bf16x8 k0 = *(const bf16x8*)&kb[(st * 16 + rA) * 64 + ((g ^ rx) << 3)];
      bf16x8 k1 = *(const bf16x8*)&kb[(st * 16 + rA) * 64 + (((4 + g) ^ rx) << 3)];
      f32x4 z = {};
      z = __builtin_amdgcn_mfma_f32_16x16x32_bf16(k0, aq0, z, 0, 0, 0);
      z = __builtin_amdgcn_mfma_f32_16x16x32_bf16(k1, aq1, z, 0, 0, 0);
      sc[st] = z;
    }
    __builtin_amdgcn_s_setprio(0);

    float a0 = fmaxf(fmaxf(sc[0][0], sc[0][1]), fmaxf(sc[0][2], sc[0][3]));
    float a1 = fmaxf(fmaxf(sc[1][0], sc[1][1]), fmaxf(sc[1][2], sc[1][3]));
    float a2 = fmaxf(fmaxf(sc[2][0], sc[2][1]), fmaxf(sc[2][2], sc[2][3]));
    float a3 = fmaxf(fmaxf(sc[3][0], sc[3][1]), fmaxf(sc[3][2], sc[3][3]));
    float mx = fmaxf(fmaxf(a0, a1), fmaxf(a2, a3));
    mx = fmaxf(mx, __shfl_xor(mx, 16));
    mx = fmaxf(mx, __shfl_xor(mx, 32));
    float tm = mx * cfold;

    if (__any(tm > mrun + 8.0f)) {           // defer-max (T13)
      float mnew = fmaxf(mrun, tm);
      float sca = __builtin_amdgcn_exp2f(mrun - mnew);
      mrun = mnew;
      lacc *= sca;
#pragma unroll
      for (int f = 0; f < 4; ++f) oacc[f] *= sca;
    }

    float p[16];
#pragma unroll
    for (int st = 0; st < 4; ++st)
#pragma unroll
      for (int r = 0; r < 4; ++r)
        p[st * 4 + r] = __builtin_amdgcn_exp2f(__builtin_fmaf(sc[st][r], cfold, -mrun));

    char* psb = (char*)&Ps[wv][0];
#pragma unroll
    for (int st = 0; st < 4; ++st) {
      uint2 w;
      w.x = cvtpk(p[st * 4 + 0], p[st * 4 + 1]);
      w.y = cvtpk(p[st * 4 + 2], p[st * 4 + 3]);
      int slot = st * 2 + (g >> 1);
      *(uint2*)&psb[rA * 128 + (((slot ^ rx)) << 4) + ((g & 1) << 3)] = w;
    }
    bf16x8 pf0 = *(const bf16x8*)&psb[rA * 128 + ((g ^ rx) << 4)];
    bf16x8 pf1 = *(const bf16x8*)&psb[rA * 128 + (((4 + g) ^ rx) << 4)];

    const u16* vbl = &Vs[buf][0];
    __builtin_amdgcn_s_setprio(1);
#pragma unroll
    for (int f = 0; f < 4; ++f) {
      bf16x8 v0 = *(const bf16x8*)&vbl[(f * 16 + rA) * 64 + ((g ^ rx) << 3)];
      bf16x8 v1 = *(const bf16x8*)&vbl[(f * 16 + rA) * 64 + (((4 + g) ^ rx) << 3)];
      oacc[f] = __builtin_amdgcn_mfma_f32_16x16x32_bf16(v0, pf0, oacc[f], 0, 0, 0);
      oacc[f] = __builtin_amdgcn_mfma_f32_16x16x32_bf16(v1, pf1, oacc[f], 0, 0, 0);
    }
    lacc = __builtin_amdgcn_mfma_f32_16x16x32_bf16(ones, pf0, lacc, 0, 0, 0);
    lacc = __builtin_amdgcn_mfma_f32_16x16x32_bf16(ones, pf1, lacc, 0, 0, 0);
    __builtin_amdgcn_s_setprio(0);
  }

  float linv = 1.0f / lacc[0];
#pragma unroll
  for (int f = 0; f < 4; ++f) {
    uint2 w;
    w.x = cvtpk(oacc[f][0] * linv, oacc[f][1] * linv);
    w.y = cvtpk(oacc[f][2] * linv, oacc[f][3] * linv);
    *(uint2*)&og[((size_t)b * T_ + q0 + rA) * D_ + h * HS_ + f * 16 + g * 4] = w;
  }
}

// ---------------- host launch ----------------
extern "C" void kernel_launch(void* const* d_in, const int* in_sizes, int n_in,
                              void* d_out, int out_size, void* d_ws, size_t ws_size,
                              hipStream_t stream) {
  const float* x   = (const float*)d_in[0];
  const float* Wq  = (const float*)d_in[1];
  const float* bq  = (const float*)d_in[2];
  const float* Wk  = (const float*)d_in[3];
  const float* bk  = (const float*)d_in[4];
  const float* Wv  = (const float*)d_in[5];
  const float* bv  = (const float*)d_in[6];
  const float* Wp  = (const float*)d_in[7];
  const float* bp  = (const float*)d_in[8];
  const float* W1  = (const float*)d_in[9];
  const float* b1  = (const float*)d_in[10];
  const float* W2  = (const float*)d_in[11];
  const float* b2  = (const float*)d_in[12];
  const float* g1  = (const float*)d_in[13];
  const float* be1 = (const float*)d_in[14];
  const float* g2  = (const float*)d_in[15];
  const float* be2 = (const float*)d_in[16];
  float* out = (float*)d_out;

  char* w = (char*)d_ws;
  auto alloc = [&](size_t bytes) { char* p = w; w += (bytes + 255) & ~(size_t)255; return p; };
  const size_t MD = (size_t)MTOT * D_;

  float* h_f    = (float*)alloc(MD * 4);   // region reused: hat_b (bf16)
  u16*   h_b    = (u16*)  alloc(MD * 2);
  u16*   wqkv_t = (u16*)  alloc(3 * (size_t)D_ * D_ * 2);
  u16*   wp_t   = (u16*)  alloc((size_t)D_ * D_ * 2);
  u16*   w1_t   = (u16*)  alloc((size_t)D_ * 4 * D_ * 2);
  u16*   w2_t   = (u16*)  alloc((size_t)D_ * 4 * D_ * 2);
  u16*   q_b    = (u16*)  alloc(MD * 2);
  u16*   k_b    = (u16*)  alloc(MD * 2);
  u16*   v_b    = (u16*)  alloc(MD * 2);   // unused as V now, kept: part of ff1_b span
  u16*   vt_b   = (u16*)  alloc(MD * 2);
  u16*   o_b    = (u16*)  alloc(MD * 2);
  float* hat_f  = (float*)alloc(MD * 4);   // region reused: pb0/pb1 (bf16)
  u16*   ff1_b  = q_b;            // [4096,4096] bf16 spans q_b..vt_b
  u16*   h2_b   = h_b;
  u16*   hat_b  = (u16*)h_f;      // proj output, bf16 (h_f region free)
  u16*   pb0    = (u16*)hat_f;            // FF2 split-K partial z=0 (bf16)
  u16*   pb1    = (u16*)hat_f + MD;       // FF2 split-K partial z=1 (bf16)
  (void)v_b;

  dim3 blk(256);

  // Fused prologue: Wq/Wk/Wv + Wp/W1/W2 transposes + LN1, one dispatch
  prologue<<<dim3(16384), blk, 0, stream>>>(Wq, Wk, Wv, wqkv_t,
      Wp, W1, W2, wp_t, w1_t, w2_t, x, g1, be1, h_b);

  // QKV: 256x192 tiles -> grid 16x16 = 256 blocks = 1/CU exactly
  gemm256<0><<<dim3(16, 16), dim3(512), 0, stream>>>(h_b, wqkv_t, bq, bk, bv,
      q_b, k_b, vt_b, MTOT, 3072, 1024);

  // attn: QBLK=128, 8 waves, grid 512
  attn_kernel<<<dim3(B_ * H_ * (T_ / 128)), dim3(512), 0, stream>>>(q_b, k_b, vt_b, o_b);

  // proj: TN=64; residual h_b (bf16); writes hat_b (bf16)
  gemm_bt<2, 64><<<dim3(16, 32, 1), blk, 0, stream>>>(o_b, wp_t, bp, h_b,
      hat_b, nullptr, MTOT, 1024, 1024, 1024);

  // LN2: bf16 in -> bf16 out
  ln_kernel_b<<<dim3(MTOT), blk, 0, stream>>>(hat_b, g2, be2, h2_b);

  // FF1: TN=64 -> 2048 blocks, 36KB LDS -> 4 blocks/CU
  gemm_bt<1, 64><<<dim3(64, 32, 1), blk, 0, stream>>>(h2_b, w1_t, b1, nullptr,
      ff1_b, nullptr, MTOT, 4096, 1024, 1024);

  // FF2: TN=128 split-K x2; bf16 partials: z=0 -> pb0, z=1 -> pb1
  gemm_bt<3, 128><<<dim3(8, 32, 2), blk, 0, stream>>>(ff1_b, w2_t, nullptr, nullptr,
      pb0, pb1, MTOT, 1024, 4096, 2048);

  // out = pb0 + pb1 + b2 + h2 (f32 out)
  reduce_ff2<<<dim3(MTOT), blk, 0, stream>>>(pb0, pb1, b2, h2_b, out);
}